// Round 17
// baseline (611.105 us; speedup 1.0000x reference)
//
#include <hip/hip_runtime.h>
#include <cstdint>

#define NN 100000
#define NE 1600000
#define NG 64
#define NH 128
#define NC 10
#define EPSV 1e-5f

#define NB 782                       // (NN+127)>>7 coarse buckets (128 nodes each)
#define NBLK 512                     // histogram/scatter blocks
#define EPB ((NE + NBLK - 1) / NBLK) // 3125 edges per block
#define NSCAN (NB * NBLK)            // 400384, divisible by 1024
#define NSB (NSCAN / 1024)           // 391 scan chunks

typedef __attribute__((ext_vector_type(8))) short bf16x8;
typedef __attribute__((ext_vector_type(4))) float f32x4;
typedef __attribute__((ext_vector_type(2))) float f32x2;
typedef unsigned long long u64;
typedef unsigned char uchar;

__device__ __forceinline__ ushort f2b(float f) {
  uint u = __builtin_bit_cast(uint, f);
  u = (u + 0x7FFFu + ((u >> 16) & 1u)) >> 16;
  return (ushort)u;
}
__device__ __forceinline__ float b2f(ushort h) {
  return __builtin_bit_cast(float, ((uint)h) << 16);
}

// ---------------- merged prep: gstart/counts + zero rows + counters (blk 0),
//                  W pre-pack (blk 1..16), coarse histogram (blk 17..528) ----------------
__global__ __launch_bounds__(256) void k_prep0(const int* __restrict__ batch,
                                               int* __restrict__ gstart, int* __restrict__ counts,
                                               u64* __restrict__ zrowA, u64* __restrict__ zrowB,
                                               const float* __restrict__ W1, ushort* __restrict__ WF1,
                                               const float* __restrict__ W2, ushort* __restrict__ WF2,
                                               const int* __restrict__ ei, int* __restrict__ ghist,
                                               int* __restrict__ cnt1, int* __restrict__ cnt2) {
  int b = blockIdx.x;
  if (b == 0) {
    __shared__ int lb[NG + 1];
    int t = threadIdx.x;
    if (t <= NG) {                    // first index with batch[i] >= t (batch is sorted)
      int lo = 0, hi = NN;
      while (lo < hi) { int mid = (lo + hi) >> 1; if (batch[mid] < t) lo = mid + 1; else hi = mid; }
      lb[t] = lo;
    }
    if (t >= 96 && t < 112) zrowA[t - 96] = 0ull;   // 16 u64 = 128 B row NN
    if (t >= 112 && t < 128) zrowB[t - 112] = 0ull;
    if (t >= 128 && t < 192) cnt1[t - 128] = 0;
    if (t >= 192) cnt2[t - 192] = 0;
    __syncthreads();
    if (t < NG) { gstart[t] = lb[t]; counts[t] = lb[t + 1] - lb[t]; }
    if (t == 0) gstart[NG] = NN;
  } else if (b <= 16) {
    int tt = (b - 1) * 256 + threadIdx.x;           // 0..4095
    const float* W = (tt < 2048) ? W1 : W2;
    ushort* WF = (tt < 2048) ? WF1 : WF2;
    int t = tt & 2047;
    int lane = t & 63, nk = t >> 6;
    int n = nk >> 2, ks = nk & 3;
    int col = n * 16 + (lane & 15);
    int k0 = ks * 32 + (lane >> 4) * 8;
#pragma unroll
    for (int j = 0; j < 8; ++j) WF[(size_t)t * 8 + j] = f2b(W[(k0 + j) * NH + col]);
  } else {
    __shared__ int h[NB];
    int t = threadIdx.x, blk = b - 17;              // 0..511
    for (int i = t; i < NB; i += 256) h[i] = 0;
    __syncthreads();
    int e0 = blk * EPB, e1 = min(NE, e0 + EPB);
    for (int e = e0 + t; e < e1; e += 256) atomicAdd(&h[ei[NE + e] >> 7], 1);
    __syncthreads();
    for (int i = t; i < NB; i += 256) ghist[i * NBLK + blk] = h[i];
  }
}

// in-chunk exclusive scan (1024 elems/chunk); csums[chunk] = chunk total
__global__ __launch_bounds__(256) void k_scan1g(int* __restrict__ data, int* __restrict__ csums) {
  __shared__ int sh[256];
  int t = threadIdx.x;
  int base = blockIdx.x * 1024 + t * 4;
  int4 v = *reinterpret_cast<const int4*>(data + base);
  int s = v.x + v.y + v.z + v.w;
  sh[t] = s;
  __syncthreads();
  for (int o = 1; o < 256; o <<= 1) {
    int x = (t >= o) ? sh[t - o] : 0;
    __syncthreads();
    sh[t] += x;
    __syncthreads();
  }
  int ex = sh[t] - s;
  int4 o4;
  o4.x = ex; o4.y = ex + v.x; o4.z = ex + v.x + v.y; o4.w = ex + v.x + v.y + v.z;
  *reinterpret_cast<int4*>(data + base) = o4;
  if (t == 255) csums[blockIdx.x] = sh[255];
}

// LDS wave-scan of the NSB chunk totals -> exclusive prefix exs[0..NSB]
#define CHUNK_SCAN(csums, exs)                                            \
  {                                                                       \
    int lane_ = threadIdx.x & 63;                                         \
    if (threadIdx.x < 64) {                                               \
      int run_ = 0;                                                       \
      for (int c_ = 0; c_ < NSB; c_ += 64) {                              \
        int idx_ = c_ + lane_;                                            \
        int v_ = (idx_ < NSB) ? csums[idx_] : 0;                          \
        _Pragma("unroll")                                                 \
        for (int d_ = 1; d_ < 64; d_ <<= 1) {                             \
          int u_ = __shfl_up(v_, d_);                                     \
          if (lane_ >= d_) v_ += u_;                                      \
        }                                                                 \
        if (idx_ < NSB) exs[idx_ + 1] = run_ + v_;                        \
        run_ += __shfl(v_, 63);                                           \
      }                                                                   \
      if (lane_ == 0) exs[0] = 0;                                         \
    }                                                                     \
    __syncthreads();                                                      \
  }

// scatter: pack (dlocal, src) into one int: (d&127)<<17 | s  (s < 2^17)
__global__ __launch_bounds__(256) void k_scatter(const int* __restrict__ ei, const int* __restrict__ ghist,
                                                 const int* __restrict__ csums, int* __restrict__ tmp) {
  __shared__ int cur[NB];
  __shared__ int exs[NSB + 1];
  CHUNK_SCAN(csums, exs);
  int t = threadIdx.x, blk = blockIdx.x;
  for (int i = t; i < NB; i += 256) {
    int idx = i * NBLK + blk;
    cur[i] = ghist[idx] + exs[idx >> 10];
  }
  __syncthreads();
  int e0 = blk * EPB, e1 = min(NE, e0 + EPB);
  for (int e = e0 + t; e < e1; e += 256) {
    int d = ei[NE + e], s = ei[e];
    int p = atomicAdd(&cur[d >> 7], 1);   // LDS atomic (fast, block-local)
    tmp[p] = ((d & 127) << 17) | s;
  }
}

// fine bucket: per-node deg/offs/dis + CSR
__global__ __launch_bounds__(256) void k_fine(const int* __restrict__ tmp, const int* __restrict__ ghist,
                                              const int* __restrict__ csums,
                                              int* __restrict__ deg, int* __restrict__ offs,
                                              float* __restrict__ dis, int* __restrict__ csr) {
  __shared__ int fh[128], fsc[128], fc[128];
  __shared__ int exs[NSB + 1];
  CHUNK_SCAN(csums, exs);
  int b = blockIdx.x, t = threadIdx.x;
  int idx0 = b * NBLK;
  int bs = ghist[idx0] + exs[idx0 >> 10];
  int be = NE;
  if (b + 1 < NB) {
    int idx1 = (b + 1) * NBLK;
    be = ghist[idx1] + exs[idx1 >> 10];
  }
  if (t < 128) fh[t] = 0;
  __syncthreads();
  for (int e = bs + t; e < be; e += 256) atomicAdd(&fh[tmp[e] >> 17], 1);
  __syncthreads();
  if (t < 128) fsc[t] = fh[t];
  __syncthreads();
  for (int o = 1; o < 128; o <<= 1) {
    int x = 0;
    if (t < 128 && t >= o) x = fsc[t - o];
    __syncthreads();
    if (t < 128) fsc[t] += x;
    __syncthreads();
  }
  if (t < 128) {
    int ex = fsc[t] - fh[t];
    int node = b * 128 + t;
    fc[t] = bs + ex;
    if (node < NN) {
      deg[node] = fh[t];
      offs[node] = bs + ex;
      dis[node] = rsqrtf((float)(fh[t] + 1));   // +1 self-loop
    }
  }
  __syncthreads();
  for (int e = bs + t; e < be; e += 256) {
    int v = tmp[e];
    int p = atomicAdd(&fc[v >> 17], 1);
    csr[p] = v & 0x1FFFF;
  }
}

// ---------------- MFMA GEMM: hs_fp8 = (norm?(X) @ W) * dis ----------------
template <bool NORM>
__global__ __launch_bounds__(256) void k_gemm(const void* __restrict__ Xv, const ushort* __restrict__ WF,
                                              const float* __restrict__ dis, const int* __restrict__ batch,
                                              const float* __restrict__ Aaff, const float* __restrict__ Baff,
                                              uchar* __restrict__ out) {
  __shared__ uint sds[4][512];            // per-wave 2KB fp8 staging
  int t = threadIdx.x;
  int w = t >> 6, lane = t & 63;
  int r0 = blockIdx.x * 64 + w * 16;
  int arow = r0 + (lane & 15);
  int khi = lane >> 4;                    // 0..3
  int arowc = (arow < NN) ? arow : (NN - 1);

  f32x4 acc[8];
#pragma unroll
  for (int n = 0; n < 8; ++n) acc[n] = (f32x4){0.f, 0.f, 0.f, 0.f};

  int g = 0;
  if (NORM) g = batch[arowc];
  const bf16x8* WFv = reinterpret_cast<const bf16x8*>(WF);

#pragma unroll
  for (int ks = 0; ks < 4; ++ks) {
    int k0 = ks * 32 + khi * 8;
    bf16x8 a;
    if (!NORM) {
      const float* X = (const float*)Xv;
      float4 x0 = *reinterpret_cast<const float4*>(X + (size_t)arowc * NH + k0);
      float4 x1 = *reinterpret_cast<const float4*>(X + (size_t)arowc * NH + k0 + 4);
      a[0] = (short)f2b(x0.x); a[1] = (short)f2b(x0.y); a[2] = (short)f2b(x0.z); a[3] = (short)f2b(x0.w);
      a[4] = (short)f2b(x1.x); a[5] = (short)f2b(x1.y); a[6] = (short)f2b(x1.z); a[7] = (short)f2b(x1.w);
    } else {
      const uchar* X8 = (const uchar*)Xv;  // fp8 [node][128]
      u64 v = *reinterpret_cast<const u64*>(X8 + (size_t)arowc * NH + k0);
      uint lo = (uint)v, hi = (uint)(v >> 32);
      f32x2 x01 = __builtin_amdgcn_cvt_pk_f32_fp8((int)lo, false);
      f32x2 x23 = __builtin_amdgcn_cvt_pk_f32_fp8((int)lo, true);
      f32x2 x45 = __builtin_amdgcn_cvt_pk_f32_fp8((int)hi, false);
      f32x2 x67 = __builtin_amdgcn_cvt_pk_f32_fp8((int)hi, true);
      float4 A0 = *reinterpret_cast<const float4*>(Aaff + g * NH + k0);
      float4 A1 = *reinterpret_cast<const float4*>(Aaff + g * NH + k0 + 4);
      float4 B0 = *reinterpret_cast<const float4*>(Baff + g * NH + k0);
      float4 B1 = *reinterpret_cast<const float4*>(Baff + g * NH + k0 + 4);
      a[0] = (short)f2b(fmaf(A0.x, x01[0], B0.x));
      a[1] = (short)f2b(fmaf(A0.y, x01[1], B0.y));
      a[2] = (short)f2b(fmaf(A0.z, x23[0], B0.z));
      a[3] = (short)f2b(fmaf(A0.w, x23[1], B0.w));
      a[4] = (short)f2b(fmaf(A1.x, x45[0], B1.x));
      a[5] = (short)f2b(fmaf(A1.y, x45[1], B1.y));
      a[6] = (short)f2b(fmaf(A1.z, x67[0], B1.z));
      a[7] = (short)f2b(fmaf(A1.w, x67[1], B1.w));
    }
#pragma unroll
    for (int n = 0; n < 8; ++n) {
      bf16x8 b = WFv[(n * 4 + ks) * 64 + lane];
      acc[n] = __builtin_amdgcn_mfma_f32_16x16x32_bf16(a, b, acc[n], 0, 0, 0);
    }
  }

  // epilogue: D (col = n*16 + (lane&15), row = khi*4 + reg) -> fp8 bytes in LDS
  int colb = lane & 15;
  uchar* sb = (uchar*)sds[w];
#pragma unroll
  for (int reg = 0; reg < 4; ++reg) {
    int row = khi * 4 + reg;
    int grow = r0 + row;
    float d = (grow < NN) ? dis[grow] : 0.f;
#pragma unroll
    for (int n = 0; n < 8; n += 2) {
      int p2 = __builtin_amdgcn_cvt_pk_fp8_f32(acc[n][reg] * d, acc[n + 1][reg] * d, 0, false);
      sb[row * 128 + n * 16 + colb] = (uchar)(p2 & 0xFF);
      sb[row * 128 + (n + 1) * 16 + colb] = (uchar)((p2 >> 8) & 0xFF);
    }
  }
  __syncthreads();
  // coalesced write-out: 16 rows x 128B contiguous per wave
  const u64* ss = (const u64*)sds[w];
  u64* gout = (u64*)(out + (size_t)r0 * 128);
#pragma unroll
  for (int it = 0; it < 4; ++it) {
    int idx = it * 64 + lane;
    int row = idx >> 4;
    if (r0 + row < NN) __builtin_nontemporal_store(ss[idx], &gout[idx]);
  }
}

// ---------------- aggregation: group-owns-node, 4 nodes/wave, fp8 in/out ----------------
__global__ __launch_bounds__(256) void k_agg(const u64* __restrict__ hf8, const int* __restrict__ offs,
                                             const int* __restrict__ deg, const int* __restrict__ csr,
                                             const float* __restrict__ dis, const float* __restrict__ bias,
                                             u64* __restrict__ outb) {
  int w = threadIdx.x >> 6, lane = threadIdx.x & 63;
  int grp = lane >> 4, sub = lane & 15;
  int node = (blockIdx.x * 4 + w) * 4 + grp;   // 16 nodes per block; NN % 16 == 0
  f32x2 a01 = (f32x2){0.f, 0.f}, a23 = (f32x2){0.f, 0.f};
  f32x2 a45 = (f32x2){0.f, 0.f}, a67 = (f32x2){0.f, 0.f};
#define ACCUM(V)                                                          \
  {                                                                       \
    uint lo_ = (uint)(V), hi_ = (uint)((V) >> 32);                        \
    a01 += __builtin_amdgcn_cvt_pk_f32_fp8((int)lo_, false);              \
    a23 += __builtin_amdgcn_cvt_pk_f32_fp8((int)lo_, true);               \
    a45 += __builtin_amdgcn_cvt_pk_f32_fp8((int)hi_, false);              \
    a67 += __builtin_amdgcn_cvt_pk_f32_fp8((int)hi_, true);               \
  }
  int beg = __builtin_nontemporal_load(offs + node);
  int cnt = __builtin_nontemporal_load(deg + node);
  {                                     // self term
    u64 v = hf8[(size_t)node * 16 + sub];
    ACCUM(v);
  }
  int lim = max(beg + cnt - 1, 0);
  int endp = beg + cnt;
#define BATCH(IBASE)                                                      \
  {                                                                       \
    int pb = beg + (IBASE);                                               \
    int c_[16];                                                           \
    _Pragma("unroll")                                                     \
    for (int j = 0; j < 16; ++j)                                          \
      c_[j] = __builtin_nontemporal_load(csr + min(pb + j, lim));         \
    u64 v_[16];                                                           \
    _Pragma("unroll")                                                     \
    for (int j = 0; j < 16; ++j) {                                        \
      int s = (pb + j < endp) ? c_[j] : NN;                               \
      v_[j] = hf8[(size_t)s * 16 + sub];                                  \
    }                                                                     \
    _Pragma("unroll")                                                     \
    for (int j = 0; j < 16; ++j) ACCUM(v_[j]);                            \
  }
  BATCH(0);
  for (int i = 16; i < cnt; i += 16) BATCH(i);
#undef BATCH
#undef ACCUM
  float d = dis[node];
  float4 bA = *reinterpret_cast<const float4*>(bias + sub * 8);
  float4 bB = *reinterpret_cast<const float4*>(bias + sub * 8 + 4);
  float o0 = fmaxf(fmaf(d, a01[0], bA.x), 0.f);
  float o1 = fmaxf(fmaf(d, a01[1], bA.y), 0.f);
  float o2 = fmaxf(fmaf(d, a23[0], bA.z), 0.f);
  float o3 = fmaxf(fmaf(d, a23[1], bA.w), 0.f);
  float o4 = fmaxf(fmaf(d, a45[0], bB.x), 0.f);
  float o5 = fmaxf(fmaf(d, a45[1], bB.y), 0.f);
  float o6 = fmaxf(fmaf(d, a67[0], bB.z), 0.f);
  float o7 = fmaxf(fmaf(d, a67[1], bB.w), 0.f);
  uint b01 = (uint)__builtin_amdgcn_cvt_pk_fp8_f32(o0, o1, 0, false) & 0xFFFFu;
  uint b23 = (uint)__builtin_amdgcn_cvt_pk_fp8_f32(o2, o3, 0, false) & 0xFFFFu;
  uint b45 = (uint)__builtin_amdgcn_cvt_pk_fp8_f32(o4, o5, 0, false) & 0xFFFFu;
  uint b67 = (uint)__builtin_amdgcn_cvt_pk_fp8_f32(o6, o7, 0, false) & 0xFFFFu;
  u64 pk = (u64)(b01 | (b23 << 16)) | ((u64)(b45 | (b67 << 16)) << 32);
  __builtin_nontemporal_store(pk, &outb[(size_t)node * 16 + sub]);
}

// ---------------- GraphNorm stats + last-block finalize ----------------
// FIN==1: finalize Aaff/Baff for next layer.  FIN==2: finalize pooled + head + softmax.
template <int FIN>
__global__ __launch_bounds__(256) void k_stats(const uint* __restrict__ t8, const int* __restrict__ gstart,
                                               float* __restrict__ acc, int* __restrict__ cnt,
                                               const int* __restrict__ counts,
                                               const float* __restrict__ gw, const float* __restrict__ gb,
                                               const float* __restrict__ ga,
                                               float* __restrict__ Aaff, float* __restrict__ Baff,
                                               const float* __restrict__ Wc, const float* __restrict__ bc,
                                               float* __restrict__ outp) {
  int g = blockIdx.x >> 4, s = blockIdx.x & 15;
  int beg = gstart[g], end = gstart[g + 1];
  int j = threadIdx.x & 31, q = threadIdx.x >> 5;   // 32 uints/row (4 feats each), 8 row-groups
  f32x2 s01 = (f32x2){0.f, 0.f}, s23 = (f32x2){0.f, 0.f};
  f32x2 q01 = (f32x2){0.f, 0.f}, q23 = (f32x2){0.f, 0.f};
  for (int n = beg + s * 8 + q; n < end; n += 128) {
    uint v = t8[(size_t)n * 32 + j];
    f32x2 f01 = __builtin_amdgcn_cvt_pk_f32_fp8((int)v, false);
    f32x2 f23 = __builtin_amdgcn_cvt_pk_f32_fp8((int)v, true);
    s01 += f01; s23 += f23;
    q01 += f01 * f01; q23 += f23 * f23;
  }
  __shared__ float shs[256][4];
  __shared__ float shq[256][4];
  int t = threadIdx.x;
  shs[t][0] = s01[0]; shs[t][1] = s01[1]; shs[t][2] = s23[0]; shs[t][3] = s23[1];
  shq[t][0] = q01[0]; shq[t][1] = q01[1]; shq[t][2] = q23[0]; shq[t][3] = q23[1];
  __syncthreads();
  if (q == 0) {
    float sm[4], sq[4];
#pragma unroll
    for (int k = 0; k < 4; ++k) { sm[k] = shs[j][k]; sq[k] = shq[j][k]; }
#pragma unroll
    for (int qq = 1; qq < 8; ++qq) {
      int idx = qq * 32 + j;
#pragma unroll
      for (int k = 0; k < 4; ++k) { sm[k] += shs[idx][k]; sq[k] += shq[idx][k]; }
    }
    int f = j * 4;
    float* dst = acc + (size_t)(s * NG + g) * 2 * NH;
#pragma unroll
    for (int k = 0; k < 4; ++k) { dst[f + k] = sm[k]; dst[NH + f + k] = sq[k]; }
  }
  // last-block finalize
  __shared__ int lastFlag;
  __threadfence();                     // release partial stores (all threads)
  __syncthreads();
  if (t == 0) lastFlag = (atomicAdd(&cnt[g], 1) == 15);
  __syncthreads();
  if (!lastFlag) return;
  __threadfence();                     // acquire
  __shared__ float pool[NH];
  __shared__ float lg[NC];
  int f = t;
  if (f < NH) {
    float sum = 0.f, sq = 0.f;
#pragma unroll 4
    for (int ss = 0; ss < 16; ++ss) {
      const float* d = acc + (size_t)(ss * NG + g) * 2 * NH;
      sum += d[f];
      sq += d[NH + f];
    }
    float cntg = fmaxf((float)counts[g], 1.f);
    float m = sum / cntg;
    float ex2 = sq / cntg;
    float a = ga[f];
    float var = ex2 - 2.f * a * m * m + a * a * m * m;
    float rstd = rsqrtf(var + EPSV);
    if (FIN == 1) {
      float A = gw[f] * rstd;
      Aaff[g * NH + f] = A;
      Baff[g * NH + f] = gb[f] - A * a * m;
    } else {
      pool[f] = gw[f] * rstd * (m - a * m) + gb[f];
    }
  }
  if (FIN == 2) {
    __syncthreads();
    if (f < NC) {
      float sc = bc[f];
      for (int h = 0; h < NH; ++h) sc = fmaf(pool[h], Wc[h * NC + f], sc);
      lg[f] = sc;
    }
    __syncthreads();
    if (f == 0) {
      float mx = lg[0];
      for (int c = 1; c < NC; ++c) mx = fmaxf(mx, lg[c]);
      float ex[NC];
      float ssum = 0.f;
      for (int c = 0; c < NC; ++c) { ex[c] = __expf(lg[c] - mx); ssum += ex[c]; }
      float inv = 1.f / ssum;
      for (int c = 0; c < NC; ++c) outp[g * NC + c] = ex[c] * inv;
    }
  }
}

// ---------------- launch ----------------
extern "C" void kernel_launch(void* const* d_in, const int* in_sizes, int n_in,
                              void* d_out, int out_size, void* d_ws, size_t ws_size,
                              hipStream_t stream) {
  const float* x   = (const float*)d_in[0];
  const int*   ei  = (const int*)d_in[1];
  const int*   bat = (const int*)d_in[2];
  const float* W1  = (const float*)d_in[3];
  const float* b1  = (const float*)d_in[4];
  const float* gw1 = (const float*)d_in[5];
  const float* gb1 = (const float*)d_in[6];
  const float* ga1 = (const float*)d_in[7];
  const float* W2  = (const float*)d_in[8];
  const float* b2  = (const float*)d_in[9];
  const float* gw2 = (const float*)d_in[10];
  const float* gb2 = (const float*)d_in[11];
  const float* ga2 = (const float*)d_in[12];
  const float* Wc  = (const float*)d_in[13];
  const float* bc  = (const float*)d_in[14];
  float* outp = (float*)d_out;

  char* ws = (char*)d_ws;
  size_t off = 0;
  auto alloc = [&](size_t b) { size_t p = off; off += (b + 255) & ~(size_t)255; return p; };
  int*    deg     = (int*)(ws + alloc((size_t)NN * 4));
  float*  dis     = (float*)(ws + alloc((size_t)NN * 4));
  int*    counts  = (int*)(ws + alloc(NG * 4));
  int*    gstart  = (int*)(ws + alloc((NG + 1) * 4));
  int*    offs    = (int*)(ws + alloc((size_t)NN * 4));
  int*    csums   = (int*)(ws + alloc(512 * 4));
  int*    cnt1    = (int*)(ws + alloc(NG * 4));
  int*    cnt2    = (int*)(ws + alloc(NG * 4));
  int*    csr     = (int*)(ws + alloc((size_t)NE * 4));
  float*  statacc = (float*)(ws + alloc((size_t)16 * NG * 2 * NH * 4));   // 1 MB partials
  float*  Aaff    = (float*)(ws + alloc((size_t)NG * NH * 4));
  float*  Baff    = (float*)(ws + alloc((size_t)NG * NH * 4));
  ushort* WF1     = (ushort*)(ws + alloc((size_t)2048 * 8 * 2));
  ushort* WF2     = (ushort*)(ws + alloc((size_t)2048 * 8 * 2));
  uchar*  bufA    = (uchar*)(ws + alloc((size_t)(NN + 1) * NH));   // fp8 + zero row NN
  uchar*  bufB    = (uchar*)(ws + alloc((size_t)(NN + 1) * NH));   // fp8 + zero row NN
  // sort temps alias bufB (dead until first k_agg write): 6.4 (packed int) + 1.6 MB < 12.8 MB
  int* tmp   = (int*)bufB;
  int* ghist = (int*)((char*)bufB + (((size_t)NE * 4 + 255) & ~(size_t)255));
  (void)ws_size; (void)in_sizes; (void)n_in; (void)out_size;

  u64* zrowA = (u64*)(bufA + (size_t)NN * NH);
  u64* zrowB = (u64*)(bufB + (size_t)NN * NH);

  // prep (merged): gstart/counts + zero rows + counters + W pre-pack + coarse hist
  k_prep0<<<529, 256, 0, stream>>>(bat, gstart, counts, zrowA, zrowB, W1, WF1, W2, WF2, ei, ghist,
                                   cnt1, cnt2);
  k_scan1g<<<NSB, 256, 0, stream>>>(ghist, csums);
  k_scatter<<<NBLK, 256, 0, stream>>>(ei, ghist, csums, tmp);
  k_fine<<<NB, 256, 0, stream>>>(tmp, ghist, csums, deg, offs, dis, csr);

  int gemm_grid = (NN + 63) / 64;   // 1563
  int agg_grid  = NN / 16;          // 6250 (4 nodes per wave, group-owns-node)

  // layer 1
  k_gemm<false><<<gemm_grid, 256, 0, stream>>>(x, WF1, dis, bat, nullptr, nullptr, bufA);
  k_agg<<<agg_grid, 256, 0, stream>>>((const u64*)bufA, offs, deg, csr, dis, b1, (u64*)bufB);
  k_stats<1><<<NG * 16, 256, 0, stream>>>((const uint*)bufB, gstart, statacc, cnt1, counts,
                                          gw1, gb1, ga1, Aaff, Baff, nullptr, nullptr, nullptr);

  // layer 2 (norm fused into GEMM A-fragment load, fp8 A-input)
  k_gemm<true><<<gemm_grid, 256, 0, stream>>>(bufB, WF2, dis, bat, Aaff, Baff, bufA);
  k_agg<<<agg_grid, 256, 0, stream>>>((const u64*)bufA, offs, deg, csr, dis, b2, (u64*)bufB);
  k_stats<2><<<NG * 16, 256, 0, stream>>>((const uint*)bufB, gstart, statacc, cnt2, counts,
                                          gw2, gb2, ga2, nullptr, nullptr, Wc, bc, outp);
}

// Round 18
// 201.012 us; speedup vs baseline: 3.0401x; 3.0401x over previous
//
#include <hip/hip_runtime.h>
#include <cstdint>

#define NN 100000
#define NE 1600000
#define NG 64
#define NH 128
#define NC 10
#define EPSV 1e-5f

#define NB 782                       // (NN+127)>>7 coarse buckets (128 nodes each)
#define NBLK 512                     // histogram/scatter blocks
#define EPB ((NE + NBLK - 1) / NBLK) // 3125 edges per block
#define NSCAN (NB * NBLK)            // 400384, divisible by 1024
#define NSB (NSCAN / 1024)           // 391 scan chunks

typedef __attribute__((ext_vector_type(8))) short bf16x8;
typedef __attribute__((ext_vector_type(4))) float f32x4;
typedef __attribute__((ext_vector_type(2))) float f32x2;
typedef unsigned long long u64;
typedef unsigned char uchar;

__device__ __forceinline__ ushort f2b(float f) {
  uint u = __builtin_bit_cast(uint, f);
  u = (u + 0x7FFFu + ((u >> 16) & 1u)) >> 16;
  return (ushort)u;
}
__device__ __forceinline__ float b2f(ushort h) {
  return __builtin_bit_cast(float, ((uint)h) << 16);
}

// ---------------- merged prep: gstart/counts + zero rows (blk 0),
//                  W pre-pack (blk 1..16), coarse histogram (blk 17..528) ----------------
__global__ __launch_bounds__(256) void k_prep0(const int* __restrict__ batch,
                                               int* __restrict__ gstart, int* __restrict__ counts,
                                               u64* __restrict__ zrowA, u64* __restrict__ zrowB,
                                               const float* __restrict__ W1, ushort* __restrict__ WF1,
                                               const float* __restrict__ W2, ushort* __restrict__ WF2,
                                               const int* __restrict__ ei, int* __restrict__ ghist) {
  int b = blockIdx.x;
  if (b == 0) {
    __shared__ int lb[NG + 1];
    int t = threadIdx.x;
    if (t <= NG) {                    // first index with batch[i] >= t (batch is sorted)
      int lo = 0, hi = NN;
      while (lo < hi) { int mid = (lo + hi) >> 1; if (batch[mid] < t) lo = mid + 1; else hi = mid; }
      lb[t] = lo;
    }
    if (t >= 96 && t < 112) zrowA[t - 96] = 0ull;   // 16 u64 = 128 B row NN
    if (t >= 112 && t < 128) zrowB[t - 112] = 0ull;
    __syncthreads();
    if (t < NG) { gstart[t] = lb[t]; counts[t] = lb[t + 1] - lb[t]; }
    if (t == 0) gstart[NG] = NN;
  } else if (b <= 16) {
    int tt = (b - 1) * 256 + threadIdx.x;           // 0..4095
    const float* W = (tt < 2048) ? W1 : W2;
    ushort* WF = (tt < 2048) ? WF1 : WF2;
    int t = tt & 2047;
    int lane = t & 63, nk = t >> 6;
    int n = nk >> 2, ks = nk & 3;
    int col = n * 16 + (lane & 15);
    int k0 = ks * 32 + (lane >> 4) * 8;
#pragma unroll
    for (int j = 0; j < 8; ++j) WF[(size_t)t * 8 + j] = f2b(W[(k0 + j) * NH + col]);
  } else {
    __shared__ int h[NB];
    int t = threadIdx.x, blk = b - 17;              // 0..511
    for (int i = t; i < NB; i += 256) h[i] = 0;
    __syncthreads();
    int e0 = blk * EPB, e1 = min(NE, e0 + EPB);
    for (int e = e0 + t; e < e1; e += 256) atomicAdd(&h[ei[NE + e] >> 7], 1);
    __syncthreads();
    for (int i = t; i < NB; i += 256) ghist[i * NBLK + blk] = h[i];
  }
}

// in-chunk exclusive scan (1024 elems/chunk); csums[chunk] = chunk total
__global__ __launch_bounds__(256) void k_scan1g(int* __restrict__ data, int* __restrict__ csums) {
  __shared__ int sh[256];
  int t = threadIdx.x;
  int base = blockIdx.x * 1024 + t * 4;
  int4 v = *reinterpret_cast<const int4*>(data + base);
  int s = v.x + v.y + v.z + v.w;
  sh[t] = s;
  __syncthreads();
  for (int o = 1; o < 256; o <<= 1) {
    int x = (t >= o) ? sh[t - o] : 0;
    __syncthreads();
    sh[t] += x;
    __syncthreads();
  }
  int ex = sh[t] - s;
  int4 o4;
  o4.x = ex; o4.y = ex + v.x; o4.z = ex + v.x + v.y; o4.w = ex + v.x + v.y + v.z;
  *reinterpret_cast<int4*>(data + base) = o4;
  if (t == 255) csums[blockIdx.x] = sh[255];
}

// LDS wave-scan of the NSB chunk totals -> exclusive prefix exs[0..NSB]
#define CHUNK_SCAN(csums, exs)                                            \
  {                                                                       \
    int lane_ = threadIdx.x & 63;                                         \
    if (threadIdx.x < 64) {                                               \
      int run_ = 0;                                                       \
      for (int c_ = 0; c_ < NSB; c_ += 64) {                              \
        int idx_ = c_ + lane_;                                            \
        int v_ = (idx_ < NSB) ? csums[idx_] : 0;                          \
        _Pragma("unroll")                                                 \
        for (int d_ = 1; d_ < 64; d_ <<= 1) {                             \
          int u_ = __shfl_up(v_, d_);                                     \
          if (lane_ >= d_) v_ += u_;                                      \
        }                                                                 \
        if (idx_ < NSB) exs[idx_ + 1] = run_ + v_;                        \
        run_ += __shfl(v_, 63);                                           \
      }                                                                   \
      if (lane_ == 0) exs[0] = 0;                                         \
    }                                                                     \
    __syncthreads();                                                      \
  }

// scatter: pack (dlocal, src) into one int: (d&127)<<17 | s  (s < 2^17)
__global__ __launch_bounds__(256) void k_scatter(const int* __restrict__ ei, const int* __restrict__ ghist,
                                                 const int* __restrict__ csums, int* __restrict__ tmp) {
  __shared__ int cur[NB];
  __shared__ int exs[NSB + 1];
  CHUNK_SCAN(csums, exs);
  int t = threadIdx.x, blk = blockIdx.x;
  for (int i = t; i < NB; i += 256) {
    int idx = i * NBLK + blk;
    cur[i] = ghist[idx] + exs[idx >> 10];
  }
  __syncthreads();
  int e0 = blk * EPB, e1 = min(NE, e0 + EPB);
  for (int e = e0 + t; e < e1; e += 256) {
    int d = ei[NE + e], s = ei[e];
    int p = atomicAdd(&cur[d >> 7], 1);   // LDS atomic (fast, block-local)
    tmp[p] = ((d & 127) << 17) | s;
  }
}

// fine bucket: per-node deg/offs/dis + CSR
__global__ __launch_bounds__(256) void k_fine(const int* __restrict__ tmp, const int* __restrict__ ghist,
                                              const int* __restrict__ csums,
                                              int* __restrict__ deg, int* __restrict__ offs,
                                              float* __restrict__ dis, int* __restrict__ csr) {
  __shared__ int fh[128], fsc[128], fc[128];
  __shared__ int exs[NSB + 1];
  CHUNK_SCAN(csums, exs);
  int b = blockIdx.x, t = threadIdx.x;
  int idx0 = b * NBLK;
  int bs = ghist[idx0] + exs[idx0 >> 10];
  int be = NE;
  if (b + 1 < NB) {
    int idx1 = (b + 1) * NBLK;
    be = ghist[idx1] + exs[idx1 >> 10];
  }
  if (t < 128) fh[t] = 0;
  __syncthreads();
  for (int e = bs + t; e < be; e += 256) atomicAdd(&fh[tmp[e] >> 17], 1);
  __syncthreads();
  if (t < 128) fsc[t] = fh[t];
  __syncthreads();
  for (int o = 1; o < 128; o <<= 1) {
    int x = 0;
    if (t < 128 && t >= o) x = fsc[t - o];
    __syncthreads();
    if (t < 128) fsc[t] += x;
    __syncthreads();
  }
  if (t < 128) {
    int ex = fsc[t] - fh[t];
    int node = b * 128 + t;
    fc[t] = bs + ex;
    if (node < NN) {
      deg[node] = fh[t];
      offs[node] = bs + ex;
      dis[node] = rsqrtf((float)(fh[t] + 1));   // +1 self-loop
    }
  }
  __syncthreads();
  for (int e = bs + t; e < be; e += 256) {
    int v = tmp[e];
    int p = atomicAdd(&fc[v >> 17], 1);
    csr[p] = v & 0x1FFFF;
  }
}

// ---------------- MFMA GEMM: hs_fp8 = (norm?(X) @ W) * dis ----------------
template <bool NORM>
__global__ __launch_bounds__(256) void k_gemm(const void* __restrict__ Xv, const ushort* __restrict__ WF,
                                              const float* __restrict__ dis, const int* __restrict__ batch,
                                              const float* __restrict__ Aaff, const float* __restrict__ Baff,
                                              uchar* __restrict__ out) {
  __shared__ uint sds[4][512];            // per-wave 2KB fp8 staging
  int t = threadIdx.x;
  int w = t >> 6, lane = t & 63;
  int r0 = blockIdx.x * 64 + w * 16;
  int arow = r0 + (lane & 15);
  int khi = lane >> 4;                    // 0..3
  int arowc = (arow < NN) ? arow : (NN - 1);

  f32x4 acc[8];
#pragma unroll
  for (int n = 0; n < 8; ++n) acc[n] = (f32x4){0.f, 0.f, 0.f, 0.f};

  int g = 0;
  if (NORM) g = batch[arowc];
  const bf16x8* WFv = reinterpret_cast<const bf16x8*>(WF);

#pragma unroll
  for (int ks = 0; ks < 4; ++ks) {
    int k0 = ks * 32 + khi * 8;
    bf16x8 a;
    if (!NORM) {
      const float* X = (const float*)Xv;
      float4 x0 = *reinterpret_cast<const float4*>(X + (size_t)arowc * NH + k0);
      float4 x1 = *reinterpret_cast<const float4*>(X + (size_t)arowc * NH + k0 + 4);
      a[0] = (short)f2b(x0.x); a[1] = (short)f2b(x0.y); a[2] = (short)f2b(x0.z); a[3] = (short)f2b(x0.w);
      a[4] = (short)f2b(x1.x); a[5] = (short)f2b(x1.y); a[6] = (short)f2b(x1.z); a[7] = (short)f2b(x1.w);
    } else {
      const uchar* X8 = (const uchar*)Xv;  // fp8 [node][128]
      u64 v = *reinterpret_cast<const u64*>(X8 + (size_t)arowc * NH + k0);
      uint lo = (uint)v, hi = (uint)(v >> 32);
      f32x2 x01 = __builtin_amdgcn_cvt_pk_f32_fp8((int)lo, false);
      f32x2 x23 = __builtin_amdgcn_cvt_pk_f32_fp8((int)lo, true);
      f32x2 x45 = __builtin_amdgcn_cvt_pk_f32_fp8((int)hi, false);
      f32x2 x67 = __builtin_amdgcn_cvt_pk_f32_fp8((int)hi, true);
      float4 A0 = *reinterpret_cast<const float4*>(Aaff + g * NH + k0);
      float4 A1 = *reinterpret_cast<const float4*>(Aaff + g * NH + k0 + 4);
      float4 B0 = *reinterpret_cast<const float4*>(Baff + g * NH + k0);
      float4 B1 = *reinterpret_cast<const float4*>(Baff + g * NH + k0 + 4);
      a[0] = (short)f2b(fmaf(A0.x, x01[0], B0.x));
      a[1] = (short)f2b(fmaf(A0.y, x01[1], B0.y));
      a[2] = (short)f2b(fmaf(A0.z, x23[0], B0.z));
      a[3] = (short)f2b(fmaf(A0.w, x23[1], B0.w));
      a[4] = (short)f2b(fmaf(A1.x, x45[0], B1.x));
      a[5] = (short)f2b(fmaf(A1.y, x45[1], B1.y));
      a[6] = (short)f2b(fmaf(A1.z, x67[0], B1.z));
      a[7] = (short)f2b(fmaf(A1.w, x67[1], B1.w));
    }
#pragma unroll
    for (int n = 0; n < 8; ++n) {
      bf16x8 b = WFv[(n * 4 + ks) * 64 + lane];
      acc[n] = __builtin_amdgcn_mfma_f32_16x16x32_bf16(a, b, acc[n], 0, 0, 0);
    }
  }

  // epilogue: D (col = n*16 + (lane&15), row = khi*4 + reg) -> fp8 bytes in LDS
  int colb = lane & 15;
  uchar* sb = (uchar*)sds[w];
#pragma unroll
  for (int reg = 0; reg < 4; ++reg) {
    int row = khi * 4 + reg;
    int grow = r0 + row;
    float d = (grow < NN) ? dis[grow] : 0.f;
#pragma unroll
    for (int n = 0; n < 8; n += 2) {
      int p2 = __builtin_amdgcn_cvt_pk_fp8_f32(acc[n][reg] * d, acc[n + 1][reg] * d, 0, false);
      sb[row * 128 + n * 16 + colb] = (uchar)(p2 & 0xFF);
      sb[row * 128 + (n + 1) * 16 + colb] = (uchar)((p2 >> 8) & 0xFF);
    }
  }
  __syncthreads();
  // coalesced write-out: 16 rows x 128B contiguous per wave
  const u64* ss = (const u64*)sds[w];
  u64* gout = (u64*)(out + (size_t)r0 * 128);
#pragma unroll
  for (int it = 0; it < 4; ++it) {
    int idx = it * 64 + lane;
    int row = idx >> 4;
    if (r0 + row < NN) __builtin_nontemporal_store(ss[idx], &gout[idx]);
  }
}

// ---------------- aggregation: group-owns-node, 4 nodes/wave, fp8 in/out ----------------
__global__ __launch_bounds__(256) void k_agg(const u64* __restrict__ hf8, const int* __restrict__ offs,
                                             const int* __restrict__ deg, const int* __restrict__ csr,
                                             const float* __restrict__ dis, const float* __restrict__ bias,
                                             u64* __restrict__ outb) {
  int w = threadIdx.x >> 6, lane = threadIdx.x & 63;
  int grp = lane >> 4, sub = lane & 15;
  int node = (blockIdx.x * 4 + w) * 4 + grp;   // 16 nodes per block; NN % 16 == 0
  f32x2 a01 = (f32x2){0.f, 0.f}, a23 = (f32x2){0.f, 0.f};
  f32x2 a45 = (f32x2){0.f, 0.f}, a67 = (f32x2){0.f, 0.f};
#define ACCUM(V)                                                          \
  {                                                                       \
    uint lo_ = (uint)(V), hi_ = (uint)((V) >> 32);                        \
    a01 += __builtin_amdgcn_cvt_pk_f32_fp8((int)lo_, false);              \
    a23 += __builtin_amdgcn_cvt_pk_f32_fp8((int)lo_, true);               \
    a45 += __builtin_amdgcn_cvt_pk_f32_fp8((int)hi_, false);              \
    a67 += __builtin_amdgcn_cvt_pk_f32_fp8((int)hi_, true);               \
  }
  int beg = __builtin_nontemporal_load(offs + node);
  int cnt = __builtin_nontemporal_load(deg + node);
  {                                     // self term
    u64 v = hf8[(size_t)node * 16 + sub];
    ACCUM(v);
  }
  int lim = max(beg + cnt - 1, 0);
  int endp = beg + cnt;
#define BATCH(IBASE)                                                      \
  {                                                                       \
    int pb = beg + (IBASE);                                               \
    int c_[16];                                                           \
    _Pragma("unroll")                                                     \
    for (int j = 0; j < 16; ++j)                                          \
      c_[j] = __builtin_nontemporal_load(csr + min(pb + j, lim));         \
    u64 v_[16];                                                           \
    _Pragma("unroll")                                                     \
    for (int j = 0; j < 16; ++j) {                                        \
      int s = (pb + j < endp) ? c_[j] : NN;                               \
      v_[j] = hf8[(size_t)s * 16 + sub];                                  \
    }                                                                     \
    _Pragma("unroll")                                                     \
    for (int j = 0; j < 16; ++j) ACCUM(v_[j]);                            \
  }
  BATCH(0);
  for (int i = 16; i < cnt; i += 16) BATCH(i);
#undef BATCH
#undef ACCUM
  float d = dis[node];
  float4 bA = *reinterpret_cast<const float4*>(bias + sub * 8);
  float4 bB = *reinterpret_cast<const float4*>(bias + sub * 8 + 4);
  float o0 = fmaxf(fmaf(d, a01[0], bA.x), 0.f);
  float o1 = fmaxf(fmaf(d, a01[1], bA.y), 0.f);
  float o2 = fmaxf(fmaf(d, a23[0], bA.z), 0.f);
  float o3 = fmaxf(fmaf(d, a23[1], bA.w), 0.f);
  float o4 = fmaxf(fmaf(d, a45[0], bB.x), 0.f);
  float o5 = fmaxf(fmaf(d, a45[1], bB.y), 0.f);
  float o6 = fmaxf(fmaf(d, a67[0], bB.z), 0.f);
  float o7 = fmaxf(fmaf(d, a67[1], bB.w), 0.f);
  uint b01 = (uint)__builtin_amdgcn_cvt_pk_fp8_f32(o0, o1, 0, false) & 0xFFFFu;
  uint b23 = (uint)__builtin_amdgcn_cvt_pk_fp8_f32(o2, o3, 0, false) & 0xFFFFu;
  uint b45 = (uint)__builtin_amdgcn_cvt_pk_fp8_f32(o4, o5, 0, false) & 0xFFFFu;
  uint b67 = (uint)__builtin_amdgcn_cvt_pk_fp8_f32(o6, o7, 0, false) & 0xFFFFu;
  u64 pk = (u64)(b01 | (b23 << 16)) | ((u64)(b45 | (b67 << 16)) << 32);
  __builtin_nontemporal_store(pk, &outb[(size_t)node * 16 + sub]);
}

// ---------------- GraphNorm stats: per-(g,f) sum & sumsq partials, fp8 input ----------------
__global__ __launch_bounds__(256) void k_stats(const uint* __restrict__ t8, const int* __restrict__ gstart,
                                               float* __restrict__ acc) {
  int g = blockIdx.x >> 4, s = blockIdx.x & 15;
  int beg = gstart[g], end = gstart[g + 1];
  int j = threadIdx.x & 31, q = threadIdx.x >> 5;   // 32 uints/row (4 feats each), 8 row-groups
  f32x2 s01 = (f32x2){0.f, 0.f}, s23 = (f32x2){0.f, 0.f};
  f32x2 q01 = (f32x2){0.f, 0.f}, q23 = (f32x2){0.f, 0.f};
  for (int n = beg + s * 8 + q; n < end; n += 128) {
    uint v = t8[(size_t)n * 32 + j];
    f32x2 f01 = __builtin_amdgcn_cvt_pk_f32_fp8((int)v, false);
    f32x2 f23 = __builtin_amdgcn_cvt_pk_f32_fp8((int)v, true);
    s01 += f01; s23 += f23;
    q01 += f01 * f01; q23 += f23 * f23;
  }
  __shared__ float shs[256][4];
  __shared__ float shq[256][4];
  int t = threadIdx.x;
  shs[t][0] = s01[0]; shs[t][1] = s01[1]; shs[t][2] = s23[0]; shs[t][3] = s23[1];
  shq[t][0] = q01[0]; shq[t][1] = q01[1]; shq[t][2] = q23[0]; shq[t][3] = q23[1];
  __syncthreads();
  if (q == 0) {
    float sm[4], sq[4];
#pragma unroll
    for (int k = 0; k < 4; ++k) { sm[k] = shs[j][k]; sq[k] = shq[j][k]; }
#pragma unroll
    for (int qq = 1; qq < 8; ++qq) {
      int idx = qq * 32 + j;
#pragma unroll
      for (int k = 0; k < 4; ++k) { sm[k] += shs[idx][k]; sq[k] += shq[idx][k]; }
    }
    int f = j * 4;
    float* dst = acc + (size_t)(s * NG + g) * 2 * NH;
#pragma unroll
    for (int k = 0; k < 4; ++k) { dst[f + k] = sm[k]; dst[NH + f + k] = sq[k]; }
  }
}

__global__ __launch_bounds__(128) void k_fin1(const float* __restrict__ acc, const int* __restrict__ counts,
                                              const float* __restrict__ gw, const float* __restrict__ gb,
                                              const float* __restrict__ ga,
                                              float* __restrict__ Aaff, float* __restrict__ Baff) {
  int g = blockIdx.x, f = threadIdx.x;
  float sum = 0.f, sq = 0.f;
#pragma unroll 4
  for (int s = 0; s < 16; ++s) {
    const float* d = acc + (size_t)(s * NG + g) * 2 * NH;
    sum += d[f];
    sq += d[NH + f];
  }
  float cnt = fmaxf((float)counts[g], 1.f);
  float m = sum / cnt;
  float ex2 = sq / cnt;
  float a = ga[f];
  float var = ex2 - 2.f * a * m * m + a * a * m * m;
  float rstd = rsqrtf(var + EPSV);
  float A = gw[f] * rstd;
  Aaff[g * NH + f] = A;
  Baff[g * NH + f] = gb[f] - A * a * m;
}

// fused layer-2 finalize + classifier head + softmax
__global__ __launch_bounds__(128) void k_fin2head(const float* __restrict__ acc, const int* __restrict__ counts,
                                                  const float* __restrict__ gw, const float* __restrict__ gb,
                                                  const float* __restrict__ ga, const float* __restrict__ Wc,
                                                  const float* __restrict__ bc, float* __restrict__ outp) {
  __shared__ float pool[NH];
  __shared__ float lg[NC];
  int g = blockIdx.x, f = threadIdx.x;
  float sum = 0.f, sq = 0.f;
#pragma unroll 4
  for (int s = 0; s < 16; ++s) {
    const float* d = acc + (size_t)(s * NG + g) * 2 * NH;
    sum += d[f];
    sq += d[NH + f];
  }
  float cnt = fmaxf((float)counts[g], 1.f);
  float m = sum / cnt;
  float ex2 = sq / cnt;
  float a = ga[f];
  float var = ex2 - 2.f * a * m * m + a * a * m * m;
  float rstd = rsqrtf(var + EPSV);
  pool[f] = gw[f] * rstd * (m - a * m) + gb[f];
  __syncthreads();
  if (f < NC) {
    float s = bc[f];
    for (int h = 0; h < NH; ++h) s = fmaf(pool[h], Wc[h * NC + f], s);
    lg[f] = s;
  }
  __syncthreads();
  if (f == 0) {
    float mx = lg[0];
    for (int c = 1; c < NC; ++c) mx = fmaxf(mx, lg[c]);
    float ex[NC];
    float ssum = 0.f;
    for (int c = 0; c < NC; ++c) { ex[c] = __expf(lg[c] - mx); ssum += ex[c]; }
    float inv = 1.f / ssum;
    for (int c = 0; c < NC; ++c) outp[g * NC + c] = ex[c] * inv;
  }
}

// ---------------- launch ----------------
extern "C" void kernel_launch(void* const* d_in, const int* in_sizes, int n_in,
                              void* d_out, int out_size, void* d_ws, size_t ws_size,
                              hipStream_t stream) {
  const float* x   = (const float*)d_in[0];
  const int*   ei  = (const int*)d_in[1];
  const int*   bat = (const int*)d_in[2];
  const float* W1  = (const float*)d_in[3];
  const float* b1  = (const float*)d_in[4];
  const float* gw1 = (const float*)d_in[5];
  const float* gb1 = (const float*)d_in[6];
  const float* ga1 = (const float*)d_in[7];
  const float* W2  = (const float*)d_in[8];
  const float* b2  = (const float*)d_in[9];
  const float* gw2 = (const float*)d_in[10];
  const float* gb2 = (const float*)d_in[11];
  const float* ga2 = (const float*)d_in[12];
  const float* Wc  = (const float*)d_in[13];
  const float* bc  = (const float*)d_in[14];
  float* outp = (float*)d_out;

  char* ws = (char*)d_ws;
  size_t off = 0;
  auto alloc = [&](size_t b) { size_t p = off; off += (b + 255) & ~(size_t)255; return p; };
  int*    deg     = (int*)(ws + alloc((size_t)NN * 4));
  float*  dis     = (float*)(ws + alloc((size_t)NN * 4));
  int*    counts  = (int*)(ws + alloc(NG * 4));
  int*    gstart  = (int*)(ws + alloc((NG + 1) * 4));
  int*    offs    = (int*)(ws + alloc((size_t)NN * 4));
  int*    csums   = (int*)(ws + alloc(512 * 4));
  int*    csr     = (int*)(ws + alloc((size_t)NE * 4));
  float*  statacc = (float*)(ws + alloc((size_t)16 * NG * 2 * NH * 4));   // 1 MB partials
  float*  Aaff    = (float*)(ws + alloc((size_t)NG * NH * 4));
  float*  Baff    = (float*)(ws + alloc((size_t)NG * NH * 4));
  ushort* WF1     = (ushort*)(ws + alloc((size_t)2048 * 8 * 2));
  ushort* WF2     = (ushort*)(ws + alloc((size_t)2048 * 8 * 2));
  uchar*  bufA    = (uchar*)(ws + alloc((size_t)(NN + 1) * NH));   // fp8 + zero row NN
  uchar*  bufB    = (uchar*)(ws + alloc((size_t)(NN + 1) * NH));   // fp8 + zero row NN
  // sort temps alias bufB (dead until first k_agg write): 6.4 (packed int) + 1.6 MB < 12.8 MB
  int* tmp   = (int*)bufB;
  int* ghist = (int*)((char*)bufB + (((size_t)NE * 4 + 255) & ~(size_t)255));
  (void)ws_size; (void)in_sizes; (void)n_in; (void)out_size;

  u64* zrowA = (u64*)(bufA + (size_t)NN * NH);
  u64* zrowB = (u64*)(bufB + (size_t)NN * NH);

  // prep (merged): gstart/counts + zero rows + W pre-pack + coarse hist
  k_prep0<<<529, 256, 0, stream>>>(bat, gstart, counts, zrowA, zrowB, W1, WF1, W2, WF2, ei, ghist);
  k_scan1g<<<NSB, 256, 0, stream>>>(ghist, csums);
  k_scatter<<<NBLK, 256, 0, stream>>>(ei, ghist, csums, tmp);
  k_fine<<<NB, 256, 0, stream>>>(tmp, ghist, csums, deg, offs, dis, csr);

  int gemm_grid = (NN + 63) / 64;   // 1563
  int agg_grid  = NN / 16;          // 6250 (4 nodes per wave, group-owns-node)

  // layer 1
  k_gemm<false><<<gemm_grid, 256, 0, stream>>>(x, WF1, dis, bat, nullptr, nullptr, bufA);
  k_agg<<<agg_grid, 256, 0, stream>>>((const u64*)bufA, offs, deg, csr, dis, b1, (u64*)bufB);
  k_stats<<<NG * 16, 256, 0, stream>>>((const uint*)bufB, gstart, statacc);
  k_fin1<<<NG, 128, 0, stream>>>(statacc, counts, gw1, gb1, ga1, Aaff, Baff);

  // layer 2 (norm fused into GEMM A-fragment load, fp8 A-input)
  k_gemm<true><<<gemm_grid, 256, 0, stream>>>(bufB, WF2, dis, bat, Aaff, Baff, bufA);
  k_agg<<<agg_grid, 256, 0, stream>>>((const u64*)bufA, offs, deg, csr, dis, b2, (u64*)bufB);
  k_stats<<<NG * 16, 256, 0, stream>>>((const uint*)bufB, gstart, statacc);
  k_fin2head<<<NG, 128, 0, stream>>>(statacc, counts, gw2, gb2, ga2, Wc, bc, outp);
}

// Round 19
// 185.827 us; speedup vs baseline: 3.2886x; 1.0817x over previous
//
#include <hip/hip_runtime.h>
#include <cstdint>

#define NN 100000
#define NE 1600000
#define NG 64
#define NH 128
#define NC 10
#define EPSV 1e-5f

#define NB 782                       // (NN+127)>>7 coarse buckets (128 nodes each)
#define NBLK 512                     // histogram/scatter blocks
#define EPB ((NE + NBLK - 1) / NBLK) // 3125 edges per block
#define NSCAN (NB * NBLK)            // 400384, divisible by 1024
#define NSB (NSCAN / 1024)           // 391 scan chunks

typedef __attribute__((ext_vector_type(8))) short bf16x8;
typedef __attribute__((ext_vector_type(4))) float f32x4;
typedef __attribute__((ext_vector_type(2))) float f32x2;
typedef unsigned long long u64;
typedef unsigned char uchar;

__device__ __forceinline__ ushort f2b(float f) {
  uint u = __builtin_bit_cast(uint, f);
  u = (u + 0x7FFFu + ((u >> 16) & 1u)) >> 16;
  return (ushort)u;
}
__device__ __forceinline__ float b2f(ushort h) {
  return __builtin_bit_cast(float, ((uint)h) << 16);
}

// ---------------- merged prep: gstart/counts + zero rows (blk 0),
//                  W pre-pack (blk 1..16), coarse histogram (blk 17..528) ----------------
__global__ __launch_bounds__(256) void k_prep0(const int* __restrict__ batch,
                                               int* __restrict__ gstart, int* __restrict__ counts,
                                               u64* __restrict__ zrowA, u64* __restrict__ zrowB,
                                               const float* __restrict__ W1, ushort* __restrict__ WF1,
                                               const float* __restrict__ W2, ushort* __restrict__ WF2,
                                               const int* __restrict__ ei, int* __restrict__ ghist) {
  int b = blockIdx.x;
  if (b == 0) {
    __shared__ int lb[NG + 1];
    int t = threadIdx.x;
    if (t <= NG) {                    // first index with batch[i] >= t (batch is sorted)
      int lo = 0, hi = NN;
      while (lo < hi) { int mid = (lo + hi) >> 1; if (batch[mid] < t) lo = mid + 1; else hi = mid; }
      lb[t] = lo;
    }
    if (t >= 96 && t < 112) zrowA[t - 96] = 0ull;   // 16 u64 = 128 B row NN
    if (t >= 112 && t < 128) zrowB[t - 112] = 0ull;
    __syncthreads();
    if (t < NG) { gstart[t] = lb[t]; counts[t] = lb[t + 1] - lb[t]; }
    if (t == 0) gstart[NG] = NN;
  } else if (b <= 16) {
    int tt = (b - 1) * 256 + threadIdx.x;           // 0..4095
    const float* W = (tt < 2048) ? W1 : W2;
    ushort* WF = (tt < 2048) ? WF1 : WF2;
    int t = tt & 2047;
    int lane = t & 63, nk = t >> 6;
    int n = nk >> 2, ks = nk & 3;
    int col = n * 16 + (lane & 15);
    int k0 = ks * 32 + (lane >> 4) * 8;
#pragma unroll
    for (int j = 0; j < 8; ++j) WF[(size_t)t * 8 + j] = f2b(W[(k0 + j) * NH + col]);
  } else {
    __shared__ int h[NB];
    int t = threadIdx.x, blk = b - 17;              // 0..511
    for (int i = t; i < NB; i += 256) h[i] = 0;
    __syncthreads();
    int e0 = blk * EPB, e1 = min(NE, e0 + EPB);
    for (int e = e0 + t; e < e1; e += 256) atomicAdd(&h[ei[NE + e] >> 7], 1);
    __syncthreads();
    for (int i = t; i < NB; i += 256) ghist[i * NBLK + blk] = h[i];
  }
}

// in-chunk exclusive scan (1024 elems/chunk); csums[chunk] = chunk total
__global__ __launch_bounds__(256) void k_scan1g(int* __restrict__ data, int* __restrict__ csums) {
  __shared__ int sh[256];
  int t = threadIdx.x;
  int base = blockIdx.x * 1024 + t * 4;
  int4 v = *reinterpret_cast<const int4*>(data + base);
  int s = v.x + v.y + v.z + v.w;
  sh[t] = s;
  __syncthreads();
  for (int o = 1; o < 256; o <<= 1) {
    int x = (t >= o) ? sh[t - o] : 0;
    __syncthreads();
    sh[t] += x;
    __syncthreads();
  }
  int ex = sh[t] - s;
  int4 o4;
  o4.x = ex; o4.y = ex + v.x; o4.z = ex + v.x + v.y; o4.w = ex + v.x + v.y + v.z;
  *reinterpret_cast<int4*>(data + base) = o4;
  if (t == 255) csums[blockIdx.x] = sh[255];
}

// LDS wave-scan of the NSB chunk totals -> exclusive prefix exs[0..NSB]
#define CHUNK_SCAN(csums, exs)                                            \
  {                                                                       \
    int lane_ = threadIdx.x & 63;                                         \
    if (threadIdx.x < 64) {                                               \
      int run_ = 0;                                                       \
      for (int c_ = 0; c_ < NSB; c_ += 64) {                              \
        int idx_ = c_ + lane_;                                            \
        int v_ = (idx_ < NSB) ? csums[idx_] : 0;                          \
        _Pragma("unroll")                                                 \
        for (int d_ = 1; d_ < 64; d_ <<= 1) {                             \
          int u_ = __shfl_up(v_, d_);                                     \
          if (lane_ >= d_) v_ += u_;                                      \
        }                                                                 \
        if (idx_ < NSB) exs[idx_ + 1] = run_ + v_;                        \
        run_ += __shfl(v_, 63);                                           \
      }                                                                   \
      if (lane_ == 0) exs[0] = 0;                                         \
    }                                                                     \
    __syncthreads();                                                      \
  }

// scatter: pack (dlocal, src) into one int: (d&127)<<17 | s  (s < 2^17)
__global__ __launch_bounds__(256) void k_scatter(const int* __restrict__ ei, const int* __restrict__ ghist,
                                                 const int* __restrict__ csums, int* __restrict__ tmp) {
  __shared__ int cur[NB];
  __shared__ int exs[NSB + 1];
  CHUNK_SCAN(csums, exs);
  int t = threadIdx.x, blk = blockIdx.x;
  for (int i = t; i < NB; i += 256) {
    int idx = i * NBLK + blk;
    cur[i] = ghist[idx] + exs[idx >> 10];
  }
  __syncthreads();
  int e0 = blk * EPB, e1 = min(NE, e0 + EPB);
  for (int e = e0 + t; e < e1; e += 256) {
    int d = ei[NE + e], s = ei[e];
    int p = atomicAdd(&cur[d >> 7], 1);   // LDS atomic (fast, block-local)
    tmp[p] = ((d & 127) << 17) | s;
  }
}

// fine bucket: per-node deg/offs/dis + CSR
__global__ __launch_bounds__(256) void k_fine(const int* __restrict__ tmp, const int* __restrict__ ghist,
                                              const int* __restrict__ csums,
                                              int* __restrict__ deg, int* __restrict__ offs,
                                              float* __restrict__ dis, int* __restrict__ csr) {
  __shared__ int fh[128], fsc[128], fc[128];
  __shared__ int exs[NSB + 1];
  CHUNK_SCAN(csums, exs);
  int b = blockIdx.x, t = threadIdx.x;
  int idx0 = b * NBLK;
  int bs = ghist[idx0] + exs[idx0 >> 10];
  int be = NE;
  if (b + 1 < NB) {
    int idx1 = (b + 1) * NBLK;
    be = ghist[idx1] + exs[idx1 >> 10];
  }
  if (t < 128) fh[t] = 0;
  __syncthreads();
  for (int e = bs + t; e < be; e += 256) atomicAdd(&fh[tmp[e] >> 17], 1);
  __syncthreads();
  if (t < 128) fsc[t] = fh[t];
  __syncthreads();
  for (int o = 1; o < 128; o <<= 1) {
    int x = 0;
    if (t < 128 && t >= o) x = fsc[t - o];
    __syncthreads();
    if (t < 128) fsc[t] += x;
    __syncthreads();
  }
  if (t < 128) {
    int ex = fsc[t] - fh[t];
    int node = b * 128 + t;
    fc[t] = bs + ex;
    if (node < NN) {
      deg[node] = fh[t];
      offs[node] = bs + ex;
      dis[node] = rsqrtf((float)(fh[t] + 1));   // +1 self-loop
    }
  }
  __syncthreads();
  for (int e = bs + t; e < be; e += 256) {
    int v = tmp[e];
    int p = atomicAdd(&fc[v >> 17], 1);
    csr[p] = v & 0x1FFFF;
  }
}

// ---------------- MFMA GEMM: hs_fp8 = (norm?(X) @ W) * dis ----------------
template <bool NORM>
__global__ __launch_bounds__(256) void k_gemm(const void* __restrict__ Xv, const ushort* __restrict__ WF,
                                              const float* __restrict__ dis, const int* __restrict__ batch,
                                              const float* __restrict__ Aaff, const float* __restrict__ Baff,
                                              uchar* __restrict__ out) {
  __shared__ uint sds[4][512];            // per-wave 2KB fp8 staging
  int t = threadIdx.x;
  int w = t >> 6, lane = t & 63;
  int r0 = blockIdx.x * 64 + w * 16;
  int arow = r0 + (lane & 15);
  int khi = lane >> 4;                    // 0..3
  int arowc = (arow < NN) ? arow : (NN - 1);

  f32x4 acc[8];
#pragma unroll
  for (int n = 0; n < 8; ++n) acc[n] = (f32x4){0.f, 0.f, 0.f, 0.f};

  int g = 0;
  if (NORM) g = batch[arowc];
  const bf16x8* WFv = reinterpret_cast<const bf16x8*>(WF);

#pragma unroll
  for (int ks = 0; ks < 4; ++ks) {
    int k0 = ks * 32 + khi * 8;
    bf16x8 a;
    if (!NORM) {
      const float* X = (const float*)Xv;
      float4 x0 = *reinterpret_cast<const float4*>(X + (size_t)arowc * NH + k0);
      float4 x1 = *reinterpret_cast<const float4*>(X + (size_t)arowc * NH + k0 + 4);
      a[0] = (short)f2b(x0.x); a[1] = (short)f2b(x0.y); a[2] = (short)f2b(x0.z); a[3] = (short)f2b(x0.w);
      a[4] = (short)f2b(x1.x); a[5] = (short)f2b(x1.y); a[6] = (short)f2b(x1.z); a[7] = (short)f2b(x1.w);
    } else {
      const uchar* X8 = (const uchar*)Xv;  // fp8 [node][128]
      u64 v = *reinterpret_cast<const u64*>(X8 + (size_t)arowc * NH + k0);
      uint lo = (uint)v, hi = (uint)(v >> 32);
      f32x2 x01 = __builtin_amdgcn_cvt_pk_f32_fp8((int)lo, false);
      f32x2 x23 = __builtin_amdgcn_cvt_pk_f32_fp8((int)lo, true);
      f32x2 x45 = __builtin_amdgcn_cvt_pk_f32_fp8((int)hi, false);
      f32x2 x67 = __builtin_amdgcn_cvt_pk_f32_fp8((int)hi, true);
      float4 A0 = *reinterpret_cast<const float4*>(Aaff + g * NH + k0);
      float4 A1 = *reinterpret_cast<const float4*>(Aaff + g * NH + k0 + 4);
      float4 B0 = *reinterpret_cast<const float4*>(Baff + g * NH + k0);
      float4 B1 = *reinterpret_cast<const float4*>(Baff + g * NH + k0 + 4);
      a[0] = (short)f2b(fmaf(A0.x, x01[0], B0.x));
      a[1] = (short)f2b(fmaf(A0.y, x01[1], B0.y));
      a[2] = (short)f2b(fmaf(A0.z, x23[0], B0.z));
      a[3] = (short)f2b(fmaf(A0.w, x23[1], B0.w));
      a[4] = (short)f2b(fmaf(A1.x, x45[0], B1.x));
      a[5] = (short)f2b(fmaf(A1.y, x45[1], B1.y));
      a[6] = (short)f2b(fmaf(A1.z, x67[0], B1.z));
      a[7] = (short)f2b(fmaf(A1.w, x67[1], B1.w));
    }
#pragma unroll
    for (int n = 0; n < 8; ++n) {
      bf16x8 b = WFv[(n * 4 + ks) * 64 + lane];
      acc[n] = __builtin_amdgcn_mfma_f32_16x16x32_bf16(a, b, acc[n], 0, 0, 0);
    }
  }

  // epilogue: D (col = n*16 + (lane&15), row = khi*4 + reg) -> fp8 bytes in LDS
  int colb = lane & 15;
  uchar* sb = (uchar*)sds[w];
#pragma unroll
  for (int reg = 0; reg < 4; ++reg) {
    int row = khi * 4 + reg;
    int grow = r0 + row;
    float d = (grow < NN) ? dis[grow] : 0.f;
#pragma unroll
    for (int n = 0; n < 8; n += 2) {
      int p2 = __builtin_amdgcn_cvt_pk_fp8_f32(acc[n][reg] * d, acc[n + 1][reg] * d, 0, false);
      sb[row * 128 + n * 16 + colb] = (uchar)(p2 & 0xFF);
      sb[row * 128 + (n + 1) * 16 + colb] = (uchar)((p2 >> 8) & 0xFF);
    }
  }
  __syncthreads();
  // coalesced write-out: 16 rows x 128B contiguous per wave
  const u64* ss = (const u64*)sds[w];
  u64* gout = (u64*)(out + (size_t)r0 * 128);
#pragma unroll
  for (int it = 0; it < 4; ++it) {
    int idx = it * 64 + lane;
    int row = idx >> 4;
    if (r0 + row < NN) __builtin_nontemporal_store(ss[idx], &gout[idx]);
  }
}

// ---------------- aggregation: group-owns-node, 4 nodes/wave, fp8 in/out ----------------
// Lane sub loads ONE csr entry (coalesced); edge indices distributed via __shfl.
// Full batches unpredicated; only the trailing partial batch selects the zero row NN.
// Gather offsets are 32-bit (s*128+sub*8 < 2^24) -> saddr-form loads.
__global__ __launch_bounds__(256) void k_agg(const uchar* __restrict__ hb, const int* __restrict__ offs,
                                             const int* __restrict__ deg, const int* __restrict__ csr,
                                             const float* __restrict__ dis, const float* __restrict__ bias,
                                             u64* __restrict__ outb) {
  int w = threadIdx.x >> 6, lane = threadIdx.x & 63;
  int grp = lane >> 4, sub = lane & 15;
  int node = (blockIdx.x * 4 + w) * 4 + grp;   // 16 nodes per block; NN % 16 == 0
  int sub8 = sub * 8;
  int shbase = lane & 48;                       // group's lane base for shfl
  f32x2 a01 = (f32x2){0.f, 0.f}, a23 = (f32x2){0.f, 0.f};
  f32x2 a45 = (f32x2){0.f, 0.f}, a67 = (f32x2){0.f, 0.f};
#define ACCUM(V)                                                          \
  {                                                                       \
    uint lo_ = (uint)(V), hi_ = (uint)((V) >> 32);                        \
    a01 += __builtin_amdgcn_cvt_pk_f32_fp8((int)lo_, false);              \
    a23 += __builtin_amdgcn_cvt_pk_f32_fp8((int)lo_, true);               \
    a45 += __builtin_amdgcn_cvt_pk_f32_fp8((int)hi_, false);              \
    a67 += __builtin_amdgcn_cvt_pk_f32_fp8((int)hi_, true);               \
  }
  int beg = __builtin_nontemporal_load(offs + node);
  int cnt = __builtin_nontemporal_load(deg + node);
  {                                     // self term
    u64 v = *reinterpret_cast<const u64*>(hb + ((uint)node * 128u + (uint)sub8));
    ACCUM(v);
  }
  int nfull = cnt & ~15;
  int i = 0;
  for (; i < nfull; i += 16) {          // full 16-edge batches: no predication
    int c = __builtin_nontemporal_load(csr + beg + i + sub);   // coalesced
    u64 v_[16];
#pragma unroll
    for (int j = 0; j < 16; ++j) {
      int s = __shfl(c, shbase + j);
      v_[j] = *reinterpret_cast<const u64*>(hb + ((uint)s * 128u + (uint)sub8));
    }
#pragma unroll
    for (int j = 0; j < 16; ++j) ACCUM(v_[j]);
  }
  if (i < cnt) {                        // trailing partial batch (<=15 edges)
    int lim = beg + cnt - 1;
    int c = __builtin_nontemporal_load(csr + min(beg + i + sub, lim));
    u64 v_[16];
#pragma unroll
    for (int j = 0; j < 16; ++j) {
      int s = __shfl(c, shbase + j);
      s = (i + j < cnt) ? s : NN;       // row NN is all zeros
      v_[j] = *reinterpret_cast<const u64*>(hb + ((uint)s * 128u + (uint)sub8));
    }
#pragma unroll
    for (int j = 0; j < 16; ++j) ACCUM(v_[j]);
  }
#undef ACCUM
  float d = dis[node];
  float4 bA = *reinterpret_cast<const float4*>(bias + sub * 8);
  float4 bB = *reinterpret_cast<const float4*>(bias + sub * 8 + 4);
  float o0 = fmaxf(fmaf(d, a01[0], bA.x), 0.f);
  float o1 = fmaxf(fmaf(d, a01[1], bA.y), 0.f);
  float o2 = fmaxf(fmaf(d, a23[0], bA.z), 0.f);
  float o3 = fmaxf(fmaf(d, a23[1], bA.w), 0.f);
  float o4 = fmaxf(fmaf(d, a45[0], bB.x), 0.f);
  float o5 = fmaxf(fmaf(d, a45[1], bB.y), 0.f);
  float o6 = fmaxf(fmaf(d, a67[0], bB.z), 0.f);
  float o7 = fmaxf(fmaf(d, a67[1], bB.w), 0.f);
  uint b01 = (uint)__builtin_amdgcn_cvt_pk_fp8_f32(o0, o1, 0, false) & 0xFFFFu;
  uint b23 = (uint)__builtin_amdgcn_cvt_pk_fp8_f32(o2, o3, 0, false) & 0xFFFFu;
  uint b45 = (uint)__builtin_amdgcn_cvt_pk_fp8_f32(o4, o5, 0, false) & 0xFFFFu;
  uint b67 = (uint)__builtin_amdgcn_cvt_pk_fp8_f32(o6, o7, 0, false) & 0xFFFFu;
  u64 pk = (u64)(b01 | (b23 << 16)) | ((u64)(b45 | (b67 << 16)) << 32);
  __builtin_nontemporal_store(pk, &outb[(size_t)node * 16 + sub]);
}

// ---------------- GraphNorm stats: per-(g,f) sum & sumsq partials, fp8 input ----------------
__global__ __launch_bounds__(256) void k_stats(const uint* __restrict__ t8, const int* __restrict__ gstart,
                                               float* __restrict__ acc) {
  int g = blockIdx.x >> 4, s = blockIdx.x & 15;
  int beg = gstart[g], end = gstart[g + 1];
  int j = threadIdx.x & 31, q = threadIdx.x >> 5;   // 32 uints/row (4 feats each), 8 row-groups
  f32x2 s01 = (f32x2){0.f, 0.f}, s23 = (f32x2){0.f, 0.f};
  f32x2 q01 = (f32x2){0.f, 0.f}, q23 = (f32x2){0.f, 0.f};
  for (int n = beg + s * 8 + q; n < end; n += 128) {
    uint v = t8[(size_t)n * 32 + j];
    f32x2 f01 = __builtin_amdgcn_cvt_pk_f32_fp8((int)v, false);
    f32x2 f23 = __builtin_amdgcn_cvt_pk_f32_fp8((int)v, true);
    s01 += f01; s23 += f23;
    q01 += f01 * f01; q23 += f23 * f23;
  }
  __shared__ float shs[256][4];
  __shared__ float shq[256][4];
  int t = threadIdx.x;
  shs[t][0] = s01[0]; shs[t][1] = s01[1]; shs[t][2] = s23[0]; shs[t][3] = s23[1];
  shq[t][0] = q01[0]; shq[t][1] = q01[1]; shq[t][2] = q23[0]; shq[t][3] = q23[1];
  __syncthreads();
  if (q == 0) {
    float sm[4], sq[4];
#pragma unroll
    for (int k = 0; k < 4; ++k) { sm[k] = shs[j][k]; sq[k] = shq[j][k]; }
#pragma unroll
    for (int qq = 1; qq < 8; ++qq) {
      int idx = qq * 32 + j;
#pragma unroll
      for (int k = 0; k < 4; ++k) { sm[k] += shs[idx][k]; sq[k] += shq[idx][k]; }
    }
    int f = j * 4;
    float* dst = acc + (size_t)(s * NG + g) * 2 * NH;
#pragma unroll
    for (int k = 0; k < 4; ++k) { dst[f + k] = sm[k]; dst[NH + f + k] = sq[k]; }
  }
}

__global__ __launch_bounds__(128) void k_fin1(const float* __restrict__ acc, const int* __restrict__ counts,
                                              const float* __restrict__ gw, const float* __restrict__ gb,
                                              const float* __restrict__ ga,
                                              float* __restrict__ Aaff, float* __restrict__ Baff) {
  int g = blockIdx.x, f = threadIdx.x;
  float sum = 0.f, sq = 0.f;
#pragma unroll 4
  for (int s = 0; s < 16; ++s) {
    const float* d = acc + (size_t)(s * NG + g) * 2 * NH;
    sum += d[f];
    sq += d[NH + f];
  }
  float cnt = fmaxf((float)counts[g], 1.f);
  float m = sum / cnt;
  float ex2 = sq / cnt;
  float a = ga[f];
  float var = ex2 - 2.f * a * m * m + a * a * m * m;
  float rstd = rsqrtf(var + EPSV);
  float A = gw[f] * rstd;
  Aaff[g * NH + f] = A;
  Baff[g * NH + f] = gb[f] - A * a * m;
}

// fused layer-2 finalize + classifier head + softmax
__global__ __launch_bounds__(128) void k_fin2head(const float* __restrict__ acc, const int* __restrict__ counts,
                                                  const float* __restrict__ gw, const float* __restrict__ gb,
                                                  const float* __restrict__ ga, const float* __restrict__ Wc,
                                                  const float* __restrict__ bc, float* __restrict__ outp) {
  __shared__ float pool[NH];
  __shared__ float lg[NC];
  int g = blockIdx.x, f = threadIdx.x;
  float sum = 0.f, sq = 0.f;
#pragma unroll 4
  for (int s = 0; s < 16; ++s) {
    const float* d = acc + (size_t)(s * NG + g) * 2 * NH;
    sum += d[f];
    sq += d[NH + f];
  }
  float cnt = fmaxf((float)counts[g], 1.f);
  float m = sum / cnt;
  float ex2 = sq / cnt;
  float a = ga[f];
  float var = ex2 - 2.f * a * m * m + a * a * m * m;
  float rstd = rsqrtf(var + EPSV);
  pool[f] = gw[f] * rstd * (m - a * m) + gb[f];
  __syncthreads();
  if (f < NC) {
    float s = bc[f];
    for (int h = 0; h < NH; ++h) s = fmaf(pool[h], Wc[h * NC + f], s);
    lg[f] = s;
  }
  __syncthreads();
  if (f == 0) {
    float mx = lg[0];
    for (int c = 1; c < NC; ++c) mx = fmaxf(mx, lg[c]);
    float ex[NC];
    float ssum = 0.f;
    for (int c = 0; c < NC; ++c) { ex[c] = __expf(lg[c] - mx); ssum += ex[c]; }
    float inv = 1.f / ssum;
    for (int c = 0; c < NC; ++c) outp[g * NC + c] = ex[c] * inv;
  }
}

// ---------------- launch ----------------
extern "C" void kernel_launch(void* const* d_in, const int* in_sizes, int n_in,
                              void* d_out, int out_size, void* d_ws, size_t ws_size,
                              hipStream_t stream) {
  const float* x   = (const float*)d_in[0];
  const int*   ei  = (const int*)d_in[1];
  const int*   bat = (const int*)d_in[2];
  const float* W1  = (const float*)d_in[3];
  const float* b1  = (const float*)d_in[4];
  const float* gw1 = (const float*)d_in[5];
  const float* gb1 = (const float*)d_in[6];
  const float* ga1 = (const float*)d_in[7];
  const float* W2  = (const float*)d_in[8];
  const float* b2  = (const float*)d_in[9];
  const float* gw2 = (const float*)d_in[10];
  const float* gb2 = (const float*)d_in[11];
  const float* ga2 = (const float*)d_in[12];
  const float* Wc  = (const float*)d_in[13];
  const float* bc  = (const float*)d_in[14];
  float* outp = (float*)d_out;

  char* ws = (char*)d_ws;
  size_t off = 0;
  auto alloc = [&](size_t b) { size_t p = off; off += (b + 255) & ~(size_t)255; return p; };
  int*    deg     = (int*)(ws + alloc((size_t)NN * 4));
  float*  dis     = (float*)(ws + alloc((size_t)NN * 4));
  int*    counts  = (int*)(ws + alloc(NG * 4));
  int*    gstart  = (int*)(ws + alloc((NG + 1) * 4));
  int*    offs    = (int*)(ws + alloc((size_t)NN * 4));
  int*    csums   = (int*)(ws + alloc(512 * 4));
  int*    csr     = (int*)(ws + alloc((size_t)NE * 4));
  float*  statacc = (float*)(ws + alloc((size_t)16 * NG * 2 * NH * 4));   // 1 MB partials
  float*  Aaff    = (float*)(ws + alloc((size_t)NG * NH * 4));
  float*  Baff    = (float*)(ws + alloc((size_t)NG * NH * 4));
  ushort* WF1     = (ushort*)(ws + alloc((size_t)2048 * 8 * 2));
  ushort* WF2     = (ushort*)(ws + alloc((size_t)2048 * 8 * 2));
  uchar*  bufA    = (uchar*)(ws + alloc((size_t)(NN + 1) * NH));   // fp8 + zero row NN
  uchar*  bufB    = (uchar*)(ws + alloc((size_t)(NN + 1) * NH));   // fp8 + zero row NN
  // sort temps alias bufB (dead until first k_agg write): 6.4 (packed int) + 1.6 MB < 12.8 MB
  int* tmp   = (int*)bufB;
  int* ghist = (int*)((char*)bufB + (((size_t)NE * 4 + 255) & ~(size_t)255));
  (void)ws_size; (void)in_sizes; (void)n_in; (void)out_size;

  u64* zrowA = (u64*)(bufA + (size_t)NN * NH);
  u64* zrowB = (u64*)(bufB + (size_t)NN * NH);

  // prep (merged): gstart/counts + zero rows + W pre-pack + coarse hist
  k_prep0<<<529, 256, 0, stream>>>(bat, gstart, counts, zrowA, zrowB, W1, WF1, W2, WF2, ei, ghist);
  k_scan1g<<<NSB, 256, 0, stream>>>(ghist, csums);
  k_scatter<<<NBLK, 256, 0, stream>>>(ei, ghist, csums, tmp);
  k_fine<<<NB, 256, 0, stream>>>(tmp, ghist, csums, deg, offs, dis, csr);

  int gemm_grid = (NN + 63) / 64;   // 1563
  int agg_grid  = NN / 16;          // 6250 (4 nodes per wave, group-owns-node)

  // layer 1
  k_gemm<false><<<gemm_grid, 256, 0, stream>>>(x, WF1, dis, bat, nullptr, nullptr, bufA);
  k_agg<<<agg_grid, 256, 0, stream>>>(bufA, offs, deg, csr, dis, b1, (u64*)bufB);
  k_stats<<<NG * 16, 256, 0, stream>>>((const uint*)bufB, gstart, statacc);
  k_fin1<<<NG, 128, 0, stream>>>(statacc, counts, gw1, gb1, ga1, Aaff, Baff);

  // layer 2 (norm fused into GEMM A-fragment load, fp8 A-input)
  k_gemm<true><<<gemm_grid, 256, 0, stream>>>(bufB, WF2, dis, bat, Aaff, Baff, bufA);
  k_agg<<<agg_grid, 256, 0, stream>>>(bufA, offs, deg, csr, dis, b2, (u64*)bufB);
  k_stats<<<NG * 16, 256, 0, stream>>>((const uint*)bufB, gstart, statacc);
  k_fin2head<<<NG, 128, 0, stream>>>(statacc, counts, gw2, gb2, ga2, Wc, bc, outp);
}

// Round 20
// 183.768 us; speedup vs baseline: 3.3254x; 1.0112x over previous
//
#include <hip/hip_runtime.h>
#include <cstdint>

#define NN 100000
#define NE 1600000
#define NG 64
#define NH 128
#define NC 10
#define EPSV 1e-5f

#define NB 782                       // (NN+127)>>7 coarse buckets (128 nodes each)
#define NBLK 512                     // histogram/scatter blocks
#define EPB ((NE + NBLK - 1) / NBLK) // 3125 edges per block
#define NSCAN (NB * NBLK)            // 400384, divisible by 1024
#define NSB (NSCAN / 1024)           // 391 scan chunks

typedef __attribute__((ext_vector_type(8))) short bf16x8;
typedef __attribute__((ext_vector_type(4))) float f32x4;
typedef __attribute__((ext_vector_type(2))) float f32x2;
typedef unsigned long long u64;
typedef unsigned char uchar;

__device__ __forceinline__ ushort f2b(float f) {
  uint u = __builtin_bit_cast(uint, f);
  u = (u + 0x7FFFu + ((u >> 16) & 1u)) >> 16;
  return (ushort)u;
}
__device__ __forceinline__ float b2f(ushort h) {
  return __builtin_bit_cast(float, ((uint)h) << 16);
}

// ---------------- merged prep: gstart/counts + zero rows (blk 0),
//                  W pre-pack (blk 1..16), coarse histogram (blk 17..528) ----------------
__global__ __launch_bounds__(256) void k_prep0(const int* __restrict__ batch,
                                               int* __restrict__ gstart, int* __restrict__ counts,
                                               u64* __restrict__ zrowA, u64* __restrict__ zrowB,
                                               const float* __restrict__ W1, ushort* __restrict__ WF1,
                                               const float* __restrict__ W2, ushort* __restrict__ WF2,
                                               const int* __restrict__ ei, int* __restrict__ ghist) {
  int b = blockIdx.x;
  if (b == 0) {
    __shared__ int lb[NG + 1];
    int t = threadIdx.x;
    if (t <= NG) {                    // first index with batch[i] >= t (batch is sorted)
      int lo = 0, hi = NN;
      while (lo < hi) { int mid = (lo + hi) >> 1; if (batch[mid] < t) lo = mid + 1; else hi = mid; }
      lb[t] = lo;
    }
    if (t >= 96 && t < 112) zrowA[t - 96] = 0ull;   // 16 u64 = 128 B row NN
    if (t >= 112 && t < 128) zrowB[t - 112] = 0ull;
    __syncthreads();
    if (t < NG) { gstart[t] = lb[t]; counts[t] = lb[t + 1] - lb[t]; }
    if (t == 0) gstart[NG] = NN;
  } else if (b <= 16) {
    int tt = (b - 1) * 256 + threadIdx.x;           // 0..4095
    const float* W = (tt < 2048) ? W1 : W2;
    ushort* WF = (tt < 2048) ? WF1 : WF2;
    int t = tt & 2047;
    int lane = t & 63, nk = t >> 6;
    int n = nk >> 2, ks = nk & 3;
    int col = n * 16 + (lane & 15);
    int k0 = ks * 32 + (lane >> 4) * 8;
#pragma unroll
    for (int j = 0; j < 8; ++j) WF[(size_t)t * 8 + j] = f2b(W[(k0 + j) * NH + col]);
  } else {
    __shared__ int h[NB];
    int t = threadIdx.x, blk = b - 17;              // 0..511
    for (int i = t; i < NB; i += 256) h[i] = 0;
    __syncthreads();
    int e0 = blk * EPB, e1 = min(NE, e0 + EPB);
    for (int e = e0 + t; e < e1; e += 256) atomicAdd(&h[ei[NE + e] >> 7], 1);
    __syncthreads();
    for (int i = t; i < NB; i += 256) ghist[i * NBLK + blk] = h[i];
  }
}

// in-chunk exclusive scan (1024 elems/chunk); csums[chunk] = chunk total
__global__ __launch_bounds__(256) void k_scan1g(int* __restrict__ data, int* __restrict__ csums) {
  __shared__ int sh[256];
  int t = threadIdx.x;
  int base = blockIdx.x * 1024 + t * 4;
  int4 v = *reinterpret_cast<const int4*>(data + base);
  int s = v.x + v.y + v.z + v.w;
  sh[t] = s;
  __syncthreads();
  for (int o = 1; o < 256; o <<= 1) {
    int x = (t >= o) ? sh[t - o] : 0;
    __syncthreads();
    sh[t] += x;
    __syncthreads();
  }
  int ex = sh[t] - s;
  int4 o4;
  o4.x = ex; o4.y = ex + v.x; o4.z = ex + v.x + v.y; o4.w = ex + v.x + v.y + v.z;
  *reinterpret_cast<int4*>(data + base) = o4;
  if (t == 255) csums[blockIdx.x] = sh[255];
}

// LDS wave-scan of the NSB chunk totals -> exclusive prefix exs[0..NSB]
#define CHUNK_SCAN(csums, exs)                                            \
  {                                                                       \
    int lane_ = threadIdx.x & 63;                                         \
    if (threadIdx.x < 64) {                                               \
      int run_ = 0;                                                       \
      for (int c_ = 0; c_ < NSB; c_ += 64) {                              \
        int idx_ = c_ + lane_;                                            \
        int v_ = (idx_ < NSB) ? csums[idx_] : 0;                          \
        _Pragma("unroll")                                                 \
        for (int d_ = 1; d_ < 64; d_ <<= 1) {                             \
          int u_ = __shfl_up(v_, d_);                                     \
          if (lane_ >= d_) v_ += u_;                                      \
        }                                                                 \
        if (idx_ < NSB) exs[idx_ + 1] = run_ + v_;                        \
        run_ += __shfl(v_, 63);                                           \
      }                                                                   \
      if (lane_ == 0) exs[0] = 0;                                         \
    }                                                                     \
    __syncthreads();                                                      \
  }

// scatter: pack (dlocal, src) into one int: (d&127)<<17 | s  (s < 2^17)
__global__ __launch_bounds__(256) void k_scatter(const int* __restrict__ ei, const int* __restrict__ ghist,
                                                 const int* __restrict__ csums, int* __restrict__ tmp) {
  __shared__ int cur[NB];
  __shared__ int exs[NSB + 1];
  CHUNK_SCAN(csums, exs);
  int t = threadIdx.x, blk = blockIdx.x;
  for (int i = t; i < NB; i += 256) {
    int idx = i * NBLK + blk;
    cur[i] = ghist[idx] + exs[idx >> 10];
  }
  __syncthreads();
  int e0 = blk * EPB, e1 = min(NE, e0 + EPB);
  for (int e = e0 + t; e < e1; e += 256) {
    int d = ei[NE + e], s = ei[e];
    int p = atomicAdd(&cur[d >> 7], 1);   // LDS atomic (fast, block-local)
    tmp[p] = ((d & 127) << 17) | s;
  }
}

// fine bucket: per-node deg/offs/dis + CSR
__global__ __launch_bounds__(256) void k_fine(const int* __restrict__ tmp, const int* __restrict__ ghist,
                                              const int* __restrict__ csums,
                                              int* __restrict__ deg, int* __restrict__ offs,
                                              float* __restrict__ dis, int* __restrict__ csr) {
  __shared__ int fh[128], fsc[128], fc[128];
  __shared__ int exs[NSB + 1];
  CHUNK_SCAN(csums, exs);
  int b = blockIdx.x, t = threadIdx.x;
  int idx0 = b * NBLK;
  int bs = ghist[idx0] + exs[idx0 >> 10];
  int be = NE;
  if (b + 1 < NB) {
    int idx1 = (b + 1) * NBLK;
    be = ghist[idx1] + exs[idx1 >> 10];
  }
  if (t < 128) fh[t] = 0;
  __syncthreads();
  for (int e = bs + t; e < be; e += 256) atomicAdd(&fh[tmp[e] >> 17], 1);
  __syncthreads();
  if (t < 128) fsc[t] = fh[t];
  __syncthreads();
  for (int o = 1; o < 128; o <<= 1) {
    int x = 0;
    if (t < 128 && t >= o) x = fsc[t - o];
    __syncthreads();
    if (t < 128) fsc[t] += x;
    __syncthreads();
  }
  if (t < 128) {
    int ex = fsc[t] - fh[t];
    int node = b * 128 + t;
    fc[t] = bs + ex;
    if (node < NN) {
      deg[node] = fh[t];
      offs[node] = bs + ex;
      dis[node] = rsqrtf((float)(fh[t] + 1));   // +1 self-loop
    }
  }
  __syncthreads();
  for (int e = bs + t; e < be; e += 256) {
    int v = tmp[e];
    int p = atomicAdd(&fc[v >> 17], 1);
    csr[p] = v & 0x1FFFF;
  }
}

// ---------------- MFMA GEMM: hs_fp8 = (norm?(X) @ W) * dis ----------------
template <bool NORM>
__global__ __launch_bounds__(256) void k_gemm(const void* __restrict__ Xv, const ushort* __restrict__ WF,
                                              const float* __restrict__ dis, const int* __restrict__ batch,
                                              const float* __restrict__ Aaff, const float* __restrict__ Baff,
                                              uchar* __restrict__ out) {
  __shared__ uint sds[4][512];            // per-wave 2KB fp8 staging
  int t = threadIdx.x;
  int w = t >> 6, lane = t & 63;
  int r0 = blockIdx.x * 64 + w * 16;
  int arow = r0 + (lane & 15);
  int khi = lane >> 4;                    // 0..3
  int arowc = (arow < NN) ? arow : (NN - 1);

  f32x4 acc[8];
#pragma unroll
  for (int n = 0; n < 8; ++n) acc[n] = (f32x4){0.f, 0.f, 0.f, 0.f};

  int g = 0;
  if (NORM) g = batch[arowc];
  const bf16x8* WFv = reinterpret_cast<const bf16x8*>(WF);

#pragma unroll
  for (int ks = 0; ks < 4; ++ks) {
    int k0 = ks * 32 + khi * 8;
    bf16x8 a;
    if (!NORM) {
      const float* X = (const float*)Xv;
      float4 x0 = *reinterpret_cast<const float4*>(X + (size_t)arowc * NH + k0);
      float4 x1 = *reinterpret_cast<const float4*>(X + (size_t)arowc * NH + k0 + 4);
      a[0] = (short)f2b(x0.x); a[1] = (short)f2b(x0.y); a[2] = (short)f2b(x0.z); a[3] = (short)f2b(x0.w);
      a[4] = (short)f2b(x1.x); a[5] = (short)f2b(x1.y); a[6] = (short)f2b(x1.z); a[7] = (short)f2b(x1.w);
    } else {
      const uchar* X8 = (const uchar*)Xv;  // fp8 [node][128]
      u64 v = *reinterpret_cast<const u64*>(X8 + (size_t)arowc * NH + k0);
      uint lo = (uint)v, hi = (uint)(v >> 32);
      f32x2 x01 = __builtin_amdgcn_cvt_pk_f32_fp8((int)lo, false);
      f32x2 x23 = __builtin_amdgcn_cvt_pk_f32_fp8((int)lo, true);
      f32x2 x45 = __builtin_amdgcn_cvt_pk_f32_fp8((int)hi, false);
      f32x2 x67 = __builtin_amdgcn_cvt_pk_f32_fp8((int)hi, true);
      float4 A0 = *reinterpret_cast<const float4*>(Aaff + g * NH + k0);
      float4 A1 = *reinterpret_cast<const float4*>(Aaff + g * NH + k0 + 4);
      float4 B0 = *reinterpret_cast<const float4*>(Baff + g * NH + k0);
      float4 B1 = *reinterpret_cast<const float4*>(Baff + g * NH + k0 + 4);
      a[0] = (short)f2b(fmaf(A0.x, x01[0], B0.x));
      a[1] = (short)f2b(fmaf(A0.y, x01[1], B0.y));
      a[2] = (short)f2b(fmaf(A0.z, x23[0], B0.z));
      a[3] = (short)f2b(fmaf(A0.w, x23[1], B0.w));
      a[4] = (short)f2b(fmaf(A1.x, x45[0], B1.x));
      a[5] = (short)f2b(fmaf(A1.y, x45[1], B1.y));
      a[6] = (short)f2b(fmaf(A1.z, x67[0], B1.z));
      a[7] = (short)f2b(fmaf(A1.w, x67[1], B1.w));
    }
#pragma unroll
    for (int n = 0; n < 8; ++n) {
      bf16x8 b = WFv[(n * 4 + ks) * 64 + lane];
      acc[n] = __builtin_amdgcn_mfma_f32_16x16x32_bf16(a, b, acc[n], 0, 0, 0);
    }
  }

  // epilogue: D (col = n*16 + (lane&15), row = khi*4 + reg) -> fp8 bytes in LDS
  int colb = lane & 15;
  uchar* sb = (uchar*)sds[w];
#pragma unroll
  for (int reg = 0; reg < 4; ++reg) {
    int row = khi * 4 + reg;
    int grow = r0 + row;
    float d = (grow < NN) ? dis[grow] : 0.f;
#pragma unroll
    for (int n = 0; n < 8; n += 2) {
      int p2 = __builtin_amdgcn_cvt_pk_fp8_f32(acc[n][reg] * d, acc[n + 1][reg] * d, 0, false);
      sb[row * 128 + n * 16 + colb] = (uchar)(p2 & 0xFF);
      sb[row * 128 + (n + 1) * 16 + colb] = (uchar)((p2 >> 8) & 0xFF);
    }
  }
  __syncthreads();
  // coalesced write-out: 16 rows x 128B contiguous per wave
  const u64* ss = (const u64*)sds[w];
  u64* gout = (u64*)(out + (size_t)r0 * 128);
#pragma unroll
  for (int it = 0; it < 4; ++it) {
    int idx = it * 64 + lane;
    int row = idx >> 4;
    if (r0 + row < NN) __builtin_nontemporal_store(ss[idx], &gout[idx]);
  }
}

// ---------------- aggregation: group-owns-node, 4 nodes/wave, fp8 in/out ----------------
// Lane sub loads ONE csr entry per batch (coalesced); indices distributed via __shfl.
// csr loads SOFTWARE-PIPELINED: next batch's csr line issued before this batch's gathers,
// so consecutive batches' gather windows overlap. Full batches unpredicated; trailing
// partial batch selects zero row NN. 32-bit gather offsets.
__global__ __launch_bounds__(256) void k_agg(const uchar* __restrict__ hb, const int* __restrict__ offs,
                                             const int* __restrict__ deg, const int* __restrict__ csr,
                                             const float* __restrict__ dis, const float* __restrict__ bias,
                                             u64* __restrict__ outb) {
  int w = threadIdx.x >> 6, lane = threadIdx.x & 63;
  int grp = lane >> 4, sub = lane & 15;
  int node = (blockIdx.x * 4 + w) * 4 + grp;   // 16 nodes per block; NN % 16 == 0
  int sub8 = sub * 8;
  int shbase = lane & 48;                       // group's lane base for shfl
  f32x2 a01 = (f32x2){0.f, 0.f}, a23 = (f32x2){0.f, 0.f};
  f32x2 a45 = (f32x2){0.f, 0.f}, a67 = (f32x2){0.f, 0.f};
#define ACCUM(V)                                                          \
  {                                                                       \
    uint lo_ = (uint)(V), hi_ = (uint)((V) >> 32);                        \
    a01 += __builtin_amdgcn_cvt_pk_f32_fp8((int)lo_, false);              \
    a23 += __builtin_amdgcn_cvt_pk_f32_fp8((int)lo_, true);               \
    a45 += __builtin_amdgcn_cvt_pk_f32_fp8((int)hi_, false);              \
    a67 += __builtin_amdgcn_cvt_pk_f32_fp8((int)hi_, true);               \
  }
  int beg = __builtin_nontemporal_load(offs + node);
  int cnt = __builtin_nontemporal_load(deg + node);
  {                                     // self term
    u64 v = *reinterpret_cast<const u64*>(hb + ((uint)node * 128u + (uint)sub8));
    ACCUM(v);
  }
  if (cnt > 0) {
    int lim = beg + cnt - 1;
    int c = __builtin_nontemporal_load(csr + min(beg + sub, lim));   // batch-0 csr (clamped)
    int i = 0;
    for (; i + 16 <= cnt; i += 16) {    // full batches, next csr preloaded before gathers
      int cn = 0;
      if (i + 16 < cnt)                 // group-uniform
        cn = __builtin_nontemporal_load(csr + min(beg + i + 16 + sub, lim));
      u64 v_[16];
#pragma unroll
      for (int j = 0; j < 16; ++j) {
        int s = __shfl(c, shbase + j);
        v_[j] = *reinterpret_cast<const u64*>(hb + ((uint)s * 128u + (uint)sub8));
      }
#pragma unroll
      for (int j = 0; j < 16; ++j) ACCUM(v_[j]);
      c = cn;
    }
    if (i < cnt) {                      // trailing partial batch (<=15 edges), csr in c
      u64 v_[16];
#pragma unroll
      for (int j = 0; j < 16; ++j) {
        int s = __shfl(c, shbase + j);
        s = (i + j < cnt) ? s : NN;     // row NN is all zeros
        v_[j] = *reinterpret_cast<const u64*>(hb + ((uint)s * 128u + (uint)sub8));
      }
#pragma unroll
      for (int j = 0; j < 16; ++j) ACCUM(v_[j]);
    }
  }
#undef ACCUM
  float d = dis[node];
  float4 bA = *reinterpret_cast<const float4*>(bias + sub * 8);
  float4 bB = *reinterpret_cast<const float4*>(bias + sub * 8 + 4);
  float o0 = fmaxf(fmaf(d, a01[0], bA.x), 0.f);
  float o1 = fmaxf(fmaf(d, a01[1], bA.y), 0.f);
  float o2 = fmaxf(fmaf(d, a23[0], bA.z), 0.f);
  float o3 = fmaxf(fmaf(d, a23[1], bA.w), 0.f);
  float o4 = fmaxf(fmaf(d, a45[0], bB.x), 0.f);
  float o5 = fmaxf(fmaf(d, a45[1], bB.y), 0.f);
  float o6 = fmaxf(fmaf(d, a67[0], bB.z), 0.f);
  float o7 = fmaxf(fmaf(d, a67[1], bB.w), 0.f);
  uint b01 = (uint)__builtin_amdgcn_cvt_pk_fp8_f32(o0, o1, 0, false) & 0xFFFFu;
  uint b23 = (uint)__builtin_amdgcn_cvt_pk_fp8_f32(o2, o3, 0, false) & 0xFFFFu;
  uint b45 = (uint)__builtin_amdgcn_cvt_pk_fp8_f32(o4, o5, 0, false) & 0xFFFFu;
  uint b67 = (uint)__builtin_amdgcn_cvt_pk_fp8_f32(o6, o7, 0, false) & 0xFFFFu;
  u64 pk = (u64)(b01 | (b23 << 16)) | ((u64)(b45 | (b67 << 16)) << 32);
  __builtin_nontemporal_store(pk, &outb[(size_t)node * 16 + sub]);
}

// ---------------- GraphNorm stats: per-(g,f) sum & sumsq partials, fp8 input ----------------
__global__ __launch_bounds__(256) void k_stats(const uint* __restrict__ t8, const int* __restrict__ gstart,
                                               float* __restrict__ acc) {
  int g = blockIdx.x >> 4, s = blockIdx.x & 15;
  int beg = gstart[g], end = gstart[g + 1];
  int j = threadIdx.x & 31, q = threadIdx.x >> 5;   // 32 uints/row (4 feats each), 8 row-groups
  f32x2 s01 = (f32x2){0.f, 0.f}, s23 = (f32x2){0.f, 0.f};
  f32x2 q01 = (f32x2){0.f, 0.f}, q23 = (f32x2){0.f, 0.f};
  for (int n = beg + s * 8 + q; n < end; n += 128) {
    uint v = t8[(size_t)n * 32 + j];
    f32x2 f01 = __builtin_amdgcn_cvt_pk_f32_fp8((int)v, false);
    f32x2 f23 = __builtin_amdgcn_cvt_pk_f32_fp8((int)v, true);
    s01 += f01; s23 += f23;
    q01 += f01 * f01; q23 += f23 * f23;
  }
  __shared__ float shs[256][4];
  __shared__ float shq[256][4];
  int t = threadIdx.x;
  shs[t][0] = s01[0]; shs[t][1] = s01[1]; shs[t][2] = s23[0]; shs[t][3] = s23[1];
  shq[t][0] = q01[0]; shq[t][1] = q01[1]; shq[t][2] = q23[0]; shq[t][3] = q23[1];
  __syncthreads();
  if (q == 0) {
    float sm[4], sq[4];
#pragma unroll
    for (int k = 0; k < 4; ++k) { sm[k] = shs[j][k]; sq[k] = shq[j][k]; }
#pragma unroll
    for (int qq = 1; qq < 8; ++qq) {
      int idx = qq * 32 + j;
#pragma unroll
      for (int k = 0; k < 4; ++k) { sm[k] += shs[idx][k]; sq[k] += shq[idx][k]; }
    }
    int f = j * 4;
    float* dst = acc + (size_t)(s * NG + g) * 2 * NH;
#pragma unroll
    for (int k = 0; k < 4; ++k) { dst[f + k] = sm[k]; dst[NH + f + k] = sq[k]; }
  }
}

__global__ __launch_bounds__(128) void k_fin1(const float* __restrict__ acc, const int* __restrict__ counts,
                                              const float* __restrict__ gw, const float* __restrict__ gb,
                                              const float* __restrict__ ga,
                                              float* __restrict__ Aaff, float* __restrict__ Baff) {
  int g = blockIdx.x, f = threadIdx.x;
  float sum = 0.f, sq = 0.f;
#pragma unroll 4
  for (int s = 0; s < 16; ++s) {
    const float* d = acc + (size_t)(s * NG + g) * 2 * NH;
    sum += d[f];
    sq += d[NH + f];
  }
  float cnt = fmaxf((float)counts[g], 1.f);
  float m = sum / cnt;
  float ex2 = sq / cnt;
  float a = ga[f];
  float var = ex2 - 2.f * a * m * m + a * a * m * m;
  float rstd = rsqrtf(var + EPSV);
  float A = gw[f] * rstd;
  Aaff[g * NH + f] = A;
  Baff[g * NH + f] = gb[f] - A * a * m;
}

// fused layer-2 finalize + classifier head + softmax
__global__ __launch_bounds__(128) void k_fin2head(const float* __restrict__ acc, const int* __restrict__ counts,
                                                  const float* __restrict__ gw, const float* __restrict__ gb,
                                                  const float* __restrict__ ga, const float* __restrict__ Wc,
                                                  const float* __restrict__ bc, float* __restrict__ outp) {
  __shared__ float pool[NH];
  __shared__ float lg[NC];
  int g = blockIdx.x, f = threadIdx.x;
  float sum = 0.f, sq = 0.f;
#pragma unroll 4
  for (int s = 0; s < 16; ++s) {
    const float* d = acc + (size_t)(s * NG + g) * 2 * NH;
    sum += d[f];
    sq += d[NH + f];
  }
  float cnt = fmaxf((float)counts[g], 1.f);
  float m = sum / cnt;
  float ex2 = sq / cnt;
  float a = ga[f];
  float var = ex2 - 2.f * a * m * m + a * a * m * m;
  float rstd = rsqrtf(var + EPSV);
  pool[f] = gw[f] * rstd * (m - a * m) + gb[f];
  __syncthreads();
  if (f < NC) {
    float s = bc[f];
    for (int h = 0; h < NH; ++h) s = fmaf(pool[h], Wc[h * NC + f], s);
    lg[f] = s;
  }
  __syncthreads();
  if (f == 0) {
    float mx = lg[0];
    for (int c = 1; c < NC; ++c) mx = fmaxf(mx, lg[c]);
    float ex[NC];
    float ssum = 0.f;
    for (int c = 0; c < NC; ++c) { ex[c] = __expf(lg[c] - mx); ssum += ex[c]; }
    float inv = 1.f / ssum;
    for (int c = 0; c < NC; ++c) outp[g * NC + c] = ex[c] * inv;
  }
}

// ---------------- launch ----------------
extern "C" void kernel_launch(void* const* d_in, const int* in_sizes, int n_in,
                              void* d_out, int out_size, void* d_ws, size_t ws_size,
                              hipStream_t stream) {
  const float* x   = (const float*)d_in[0];
  const int*   ei  = (const int*)d_in[1];
  const int*   bat = (const int*)d_in[2];
  const float* W1  = (const float*)d_in[3];
  const float* b1  = (const float*)d_in[4];
  const float* gw1 = (const float*)d_in[5];
  const float* gb1 = (const float*)d_in[6];
  const float* ga1 = (const float*)d_in[7];
  const float* W2  = (const float*)d_in[8];
  const float* b2  = (const float*)d_in[9];
  const float* gw2 = (const float*)d_in[10];
  const float* gb2 = (const float*)d_in[11];
  const float* ga2 = (const float*)d_in[12];
  const float* Wc  = (const float*)d_in[13];
  const float* bc  = (const float*)d_in[14];
  float* outp = (float*)d_out;

  char* ws = (char*)d_ws;
  size_t off = 0;
  auto alloc = [&](size_t b) { size_t p = off; off += (b + 255) & ~(size_t)255; return p; };
  int*    deg     = (int*)(ws + alloc((size_t)NN * 4));
  float*  dis     = (float*)(ws + alloc((size_t)NN * 4));
  int*    counts  = (int*)(ws + alloc(NG * 4));
  int*    gstart  = (int*)(ws + alloc((NG + 1) * 4));
  int*    offs    = (int*)(ws + alloc((size_t)NN * 4));
  int*    csums   = (int*)(ws + alloc(512 * 4));
  int*    csr     = (int*)(ws + alloc((size_t)NE * 4));
  float*  statacc = (float*)(ws + alloc((size_t)16 * NG * 2 * NH * 4));   // 1 MB partials
  float*  Aaff    = (float*)(ws + alloc((size_t)NG * NH * 4));
  float*  Baff    = (float*)(ws + alloc((size_t)NG * NH * 4));
  ushort* WF1     = (ushort*)(ws + alloc((size_t)2048 * 8 * 2));
  ushort* WF2     = (ushort*)(ws + alloc((size_t)2048 * 8 * 2));
  uchar*  bufA    = (uchar*)(ws + alloc((size_t)(NN + 1) * NH));   // fp8 + zero row NN
  uchar*  bufB    = (uchar*)(ws + alloc((size_t)(NN + 1) * NH));   // fp8 + zero row NN
  // sort temps alias bufB (dead until first k_agg write): 6.4 (packed int) + 1.6 MB < 12.8 MB
  int* tmp   = (int*)bufB;
  int* ghist = (int*)((char*)bufB + (((size_t)NE * 4 + 255) & ~(size_t)255));
  (void)ws_size; (void)in_sizes; (void)n_in; (void)out_size;

  u64* zrowA = (u64*)(bufA + (size_t)NN * NH);
  u64* zrowB = (u64*)(bufB + (size_t)NN * NH);

  // prep (merged): gstart/counts + zero rows + W pre-pack + coarse hist
  k_prep0<<<529, 256, 0, stream>>>(bat, gstart, counts, zrowA, zrowB, W1, WF1, W2, WF2, ei, ghist);
  k_scan1g<<<NSB, 256, 0, stream>>>(ghist, csums);
  k_scatter<<<NBLK, 256, 0, stream>>>(ei, ghist, csums, tmp);
  k_fine<<<NB, 256, 0, stream>>>(tmp, ghist, csums, deg, offs, dis, csr);

  int gemm_grid = (NN + 63) / 64;   // 1563
  int agg_grid  = NN / 16;          // 6250 (4 nodes per wave, group-owns-node)

  // layer 1
  k_gemm<false><<<gemm_grid, 256, 0, stream>>>(x, WF1, dis, bat, nullptr, nullptr, bufA);
  k_agg<<<agg_grid, 256, 0, stream>>>(bufA, offs, deg, csr, dis, b1, (u64*)bufB);
  k_stats<<<NG * 16, 256, 0, stream>>>((const uint*)bufB, gstart, statacc);
  k_fin1<<<NG, 128, 0, stream>>>(statacc, counts, gw1, gb1, ga1, Aaff, Baff);

  // layer 2 (norm fused into GEMM A-fragment load, fp8 A-input)
  k_gemm<true><<<gemm_grid, 256, 0, stream>>>(bufB, WF2, dis, bat, Aaff, Baff, bufA);
  k_agg<<<agg_grid, 256, 0, stream>>>(bufA, offs, deg, csr, dis, b2, (u64*)bufB);
  k_stats<<<NG * 16, 256, 0, stream>>>((const uint*)bufB, gstart, statacc);
  k_fin2head<<<NG, 128, 0, stream>>>(statacc, counts, gw2, gb2, ga2, Wc, bc, outp);
}

// Round 22
// 181.687 us; speedup vs baseline: 3.3635x; 1.0115x over previous
//
#include <hip/hip_runtime.h>
#include <cstdint>

#define NN 100000
#define NE 1600000
#define NG 64
#define NH 128
#define NC 10
#define EPSV 1e-5f

#define NB 782                       // (NN+127)>>7 coarse buckets (128 nodes each)
#define NBLK 512                     // histogram/scatter blocks
#define EPB ((NE + NBLK - 1) / NBLK) // 3125 edges per block
#define NSCAN (NB * NBLK)            // 400384, divisible by 1024
#define NSB (NSCAN / 1024)           // 391 scan chunks

typedef __attribute__((ext_vector_type(8))) short bf16x8;
typedef __attribute__((ext_vector_type(4))) float f32x4;
typedef __attribute__((ext_vector_type(2))) float f32x2;
typedef unsigned long long u64;
typedef unsigned char uchar;

__device__ __forceinline__ ushort f2b(float f) {
  uint u = __builtin_bit_cast(uint, f);
  u = (u + 0x7FFFu + ((u >> 16) & 1u)) >> 16;
  return (ushort)u;
}
__device__ __forceinline__ float b2f(ushort h) {
  return __builtin_bit_cast(float, ((uint)h) << 16);
}

// ---------------- merged prep: gstart/counts + zero rows (blk 0),
//                  W pre-pack (blk 1..16), coarse histogram (blk 17..528) ----------------
__global__ __launch_bounds__(256) void k_prep0(const int* __restrict__ batch,
                                               int* __restrict__ gstart, int* __restrict__ counts,
                                               u64* __restrict__ zrowA, u64* __restrict__ zrowB,
                                               const float* __restrict__ W1, ushort* __restrict__ WF1,
                                               const float* __restrict__ W2, ushort* __restrict__ WF2,
                                               const int* __restrict__ ei, int* __restrict__ ghist) {
  int b = blockIdx.x;
  if (b == 0) {
    __shared__ int lb[NG + 1];
    int t = threadIdx.x;
    if (t <= NG) {                    // first index with batch[i] >= t (batch is sorted)
      int lo = 0, hi = NN;
      while (lo < hi) { int mid = (lo + hi) >> 1; if (batch[mid] < t) lo = mid + 1; else hi = mid; }
      lb[t] = lo;
    }
    if (t >= 96 && t < 112) zrowA[t - 96] = 0ull;   // 16 u64 = 128 B row NN
    if (t >= 112 && t < 128) zrowB[t - 112] = 0ull;
    __syncthreads();
    if (t < NG) { gstart[t] = lb[t]; counts[t] = lb[t + 1] - lb[t]; }
    if (t == 0) gstart[NG] = NN;
  } else if (b <= 16) {
    int tt = (b - 1) * 256 + threadIdx.x;           // 0..4095
    const float* W = (tt < 2048) ? W1 : W2;
    ushort* WF = (tt < 2048) ? WF1 : WF2;
    int t = tt & 2047;
    int lane = t & 63, nk = t >> 6;
    int n = nk >> 2, ks = nk & 3;
    int col = n * 16 + (lane & 15);
    int k0 = ks * 32 + (lane >> 4) * 8;
#pragma unroll
    for (int j = 0; j < 8; ++j) WF[(size_t)t * 8 + j] = f2b(W[(k0 + j) * NH + col]);
  } else {
    __shared__ int h[NB];
    int t = threadIdx.x, blk = b - 17;              // 0..511
    for (int i = t; i < NB; i += 256) h[i] = 0;
    __syncthreads();
    int e0 = blk * EPB, e1 = min(NE, e0 + EPB);
    for (int e = e0 + t; e < e1; e += 256) atomicAdd(&h[ei[NE + e] >> 7], 1);
    __syncthreads();
    for (int i = t; i < NB; i += 256) ghist[i * NBLK + blk] = h[i];
  }
}

// in-chunk exclusive scan (1024 elems/chunk); csums[chunk] = chunk total
__global__ __launch_bounds__(256) void k_scan1g(int* __restrict__ data, int* __restrict__ csums) {
  __shared__ int sh[256];
  int t = threadIdx.x;
  int base = blockIdx.x * 1024 + t * 4;
  int4 v = *reinterpret_cast<const int4*>(data + base);
  int s = v.x + v.y + v.z + v.w;
  sh[t] = s;
  __syncthreads();
  for (int o = 1; o < 256; o <<= 1) {
    int x = (t >= o) ? sh[t - o] : 0;
    __syncthreads();
    sh[t] += x;
    __syncthreads();
  }
  int ex = sh[t] - s;
  int4 o4;
  o4.x = ex; o4.y = ex + v.x; o4.z = ex + v.x + v.y; o4.w = ex + v.x + v.y + v.z;
  *reinterpret_cast<int4*>(data + base) = o4;
  if (t == 255) csums[blockIdx.x] = sh[255];
}

// LDS wave-scan of the NSB chunk totals -> exclusive prefix exs[0..NSB]
#define CHUNK_SCAN(csums, exs)                                            \
  {                                                                       \
    int lane_ = threadIdx.x & 63;                                         \
    if (threadIdx.x < 64) {                                               \
      int run_ = 0;                                                       \
      for (int c_ = 0; c_ < NSB; c_ += 64) {                              \
        int idx_ = c_ + lane_;                                            \
        int v_ = (idx_ < NSB) ? csums[idx_] : 0;                          \
        _Pragma("unroll")                                                 \
        for (int d_ = 1; d_ < 64; d_ <<= 1) {                             \
          int u_ = __shfl_up(v_, d_);                                     \
          if (lane_ >= d_) v_ += u_;                                      \
        }                                                                 \
        if (idx_ < NSB) exs[idx_ + 1] = run_ + v_;                        \
        run_ += __shfl(v_, 63);                                           \
      }                                                                   \
      if (lane_ == 0) exs[0] = 0;                                         \
    }                                                                     \
    __syncthreads();                                                      \
  }

// scatter: pack (dlocal, src) into one int: (d&127)<<17 | s  (s < 2^17)
__global__ __launch_bounds__(256) void k_scatter(const int* __restrict__ ei, const int* __restrict__ ghist,
                                                 const int* __restrict__ csums, int* __restrict__ tmp) {
  __shared__ int cur[NB];
  __shared__ int exs[NSB + 1];
  CHUNK_SCAN(csums, exs);
  int t = threadIdx.x, blk = blockIdx.x;
  for (int i = t; i < NB; i += 256) {
    int idx = i * NBLK + blk;
    cur[i] = ghist[idx] + exs[idx >> 10];
  }
  __syncthreads();
  int e0 = blk * EPB, e1 = min(NE, e0 + EPB);
  for (int e = e0 + t; e < e1; e += 256) {
    int d = ei[NE + e], s = ei[e];
    int p = atomicAdd(&cur[d >> 7], 1);   // LDS atomic (fast, block-local)
    tmp[p] = ((d & 127) << 17) | s;
  }
}

// fine bucket: per-node packed {offs,deg} (u64) + dis + CSR
__global__ __launch_bounds__(256) void k_fine(const int* __restrict__ tmp, const int* __restrict__ ghist,
                                              const int* __restrict__ csums,
                                              u64* __restrict__ od,
                                              float* __restrict__ dis, int* __restrict__ csr) {
  __shared__ int fh[128], fsc[128], fc[128];
  __shared__ int exs[NSB + 1];
  CHUNK_SCAN(csums, exs);
  int b = blockIdx.x, t = threadIdx.x;
  int idx0 = b * NBLK;
  int bs = ghist[idx0] + exs[idx0 >> 10];
  int be = NE;
  if (b + 1 < NB) {
    int idx1 = (b + 1) * NBLK;
    be = ghist[idx1] + exs[idx1 >> 10];
  }
  if (t < 128) fh[t] = 0;
  __syncthreads();
  for (int e = bs + t; e < be; e += 256) atomicAdd(&fh[tmp[e] >> 17], 1);
  __syncthreads();
  if (t < 128) fsc[t] = fh[t];
  __syncthreads();
  for (int o = 1; o < 128; o <<= 1) {
    int x = 0;
    if (t < 128 && t >= o) x = fsc[t - o];
    __syncthreads();
    if (t < 128) fsc[t] += x;
    __syncthreads();
  }
  if (t < 128) {
    int ex = fsc[t] - fh[t];
    int node = b * 128 + t;
    fc[t] = bs + ex;
    if (node < NN) {
      od[node] = (u64)(uint)(bs + ex) | ((u64)(uint)fh[t] << 32);
      dis[node] = rsqrtf((float)(fh[t] + 1));   // +1 self-loop
    }
  }
  __syncthreads();
  for (int e = bs + t; e < be; e += 256) {
    int v = tmp[e];
    int p = atomicAdd(&fc[v >> 17], 1);
    csr[p] = v & 0x1FFFF;
  }
}

// ---------------- MFMA GEMM: hs_fp8 = (norm?(X) @ W) * dis ----------------
template <bool NORM>
__global__ __launch_bounds__(256) void k_gemm(const void* __restrict__ Xv, const ushort* __restrict__ WF,
                                              const float* __restrict__ dis, const int* __restrict__ batch,
                                              const float* __restrict__ Aaff, const float* __restrict__ Baff,
                                              uchar* __restrict__ out) {
  __shared__ uint sds[4][512];            // per-wave 2KB fp8 staging
  int t = threadIdx.x;
  int w = t >> 6, lane = t & 63;
  int r0 = blockIdx.x * 64 + w * 16;
  int arow = r0 + (lane & 15);
  int khi = lane >> 4;                    // 0..3
  int arowc = (arow < NN) ? arow : (NN - 1);

  f32x4 acc[8];
#pragma unroll
  for (int n = 0; n < 8; ++n) acc[n] = (f32x4){0.f, 0.f, 0.f, 0.f};

  int g = 0;
  if (NORM) g = batch[arowc];
  const bf16x8* WFv = reinterpret_cast<const bf16x8*>(WF);

#pragma unroll
  for (int ks = 0; ks < 4; ++ks) {
    int k0 = ks * 32 + khi * 8;
    bf16x8 a;
    if (!NORM) {
      const float* X = (const float*)Xv;
      float4 x0 = *reinterpret_cast<const float4*>(X + (size_t)arowc * NH + k0);
      float4 x1 = *reinterpret_cast<const float4*>(X + (size_t)arowc * NH + k0 + 4);
      a[0] = (short)f2b(x0.x); a[1] = (short)f2b(x0.y); a[2] = (short)f2b(x0.z); a[3] = (short)f2b(x0.w);
      a[4] = (short)f2b(x1.x); a[5] = (short)f2b(x1.y); a[6] = (short)f2b(x1.z); a[7] = (short)f2b(x1.w);
    } else {
      const uchar* X8 = (const uchar*)Xv;  // fp8 [node][128]
      u64 v = *reinterpret_cast<const u64*>(X8 + (size_t)arowc * NH + k0);
      uint lo = (uint)v, hi = (uint)(v >> 32);
      f32x2 x01 = __builtin_amdgcn_cvt_pk_f32_fp8((int)lo, false);
      f32x2 x23 = __builtin_amdgcn_cvt_pk_f32_fp8((int)lo, true);
      f32x2 x45 = __builtin_amdgcn_cvt_pk_f32_fp8((int)hi, false);
      f32x2 x67 = __builtin_amdgcn_cvt_pk_f32_fp8((int)hi, true);
      float4 A0 = *reinterpret_cast<const float4*>(Aaff + g * NH + k0);
      float4 A1 = *reinterpret_cast<const float4*>(Aaff + g * NH + k0 + 4);
      float4 B0 = *reinterpret_cast<const float4*>(Baff + g * NH + k0);
      float4 B1 = *reinterpret_cast<const float4*>(Baff + g * NH + k0 + 4);
      a[0] = (short)f2b(fmaf(A0.x, x01[0], B0.x));
      a[1] = (short)f2b(fmaf(A0.y, x01[1], B0.y));
      a[2] = (short)f2b(fmaf(A0.z, x23[0], B0.z));
      a[3] = (short)f2b(fmaf(A0.w, x23[1], B0.w));
      a[4] = (short)f2b(fmaf(A1.x, x45[0], B1.x));
      a[5] = (short)f2b(fmaf(A1.y, x45[1], B1.y));
      a[6] = (short)f2b(fmaf(A1.z, x67[0], B1.z));
      a[7] = (short)f2b(fmaf(A1.w, x67[1], B1.w));
    }
#pragma unroll
    for (int n = 0; n < 8; ++n) {
      bf16x8 b = WFv[(n * 4 + ks) * 64 + lane];
      acc[n] = __builtin_amdgcn_mfma_f32_16x16x32_bf16(a, b, acc[n], 0, 0, 0);
    }
  }

  // epilogue: D (col = n*16 + (lane&15), row = khi*4 + reg) -> fp8 bytes in LDS
  int colb = lane & 15;
  uchar* sb = (uchar*)sds[w];
#pragma unroll
  for (int reg = 0; reg < 4; ++reg) {
    int row = khi * 4 + reg;
    int grow = r0 + row;
    float d = (grow < NN) ? dis[grow] : 0.f;
#pragma unroll
    for (int n = 0; n < 8; n += 2) {
      int p2 = __builtin_amdgcn_cvt_pk_fp8_f32(acc[n][reg] * d, acc[n + 1][reg] * d, 0, false);
      sb[row * 128 + n * 16 + colb] = (uchar)(p2 & 0xFF);
      sb[row * 128 + (n + 1) * 16 + colb] = (uchar)((p2 >> 8) & 0xFF);
    }
  }
  __syncthreads();
  // coalesced write-out: 16 rows x 128B contiguous per wave
  const u64* ss = (const u64*)sds[w];
  u64* gout = (u64*)(out + (size_t)r0 * 128);
#pragma unroll
  for (int it = 0; it < 4; ++it) {
    int idx = it * 64 + lane;
    int row = idx >> 4;
    if (r0 + row < NN) __builtin_nontemporal_store(ss[idx], &gout[idx]);
  }
}

// ---------------- aggregation: group-owns-node, 4 nodes/wave, fp8 in/out ----------------
// Lane sub loads ONE csr entry per batch (coalesced); indices distributed via __shfl.
// csr loads software-pipelined. Packed {offs,deg} u64 load. Trailing partial uses an
// 8-slot path when remainder <= 8 (halves wasted zero-row gathers).
__global__ __launch_bounds__(256) void k_agg(const uchar* __restrict__ hb, const u64* __restrict__ od,
                                             const int* __restrict__ csr,
                                             const float* __restrict__ dis, const float* __restrict__ bias,
                                             u64* __restrict__ outb) {
  int w = threadIdx.x >> 6, lane = threadIdx.x & 63;
  int grp = lane >> 4, sub = lane & 15;
  int node = (blockIdx.x * 4 + w) * 4 + grp;   // 16 nodes per block; NN % 16 == 0
  int sub8 = sub * 8;
  int shbase = lane & 48;                       // group's lane base for shfl
  f32x2 a01 = (f32x2){0.f, 0.f}, a23 = (f32x2){0.f, 0.f};
  f32x2 a45 = (f32x2){0.f, 0.f}, a67 = (f32x2){0.f, 0.f};
#define ACCUM(V)                                                          \
  {                                                                       \
    uint lo_ = (uint)(V), hi_ = (uint)((V) >> 32);                        \
    a01 += __builtin_amdgcn_cvt_pk_f32_fp8((int)lo_, false);              \
    a23 += __builtin_amdgcn_cvt_pk_f32_fp8((int)lo_, true);               \
    a45 += __builtin_amdgcn_cvt_pk_f32_fp8((int)hi_, false);              \
    a67 += __builtin_amdgcn_cvt_pk_f32_fp8((int)hi_, true);               \
  }
  u64 bd = __builtin_nontemporal_load(od + node);
  int beg = (int)(uint)bd;
  int cnt = (int)(uint)(bd >> 32);
  {                                     // self term
    u64 v = *reinterpret_cast<const u64*>(hb + ((uint)node * 128u + (uint)sub8));
    ACCUM(v);
  }
  if (cnt > 0) {
    int lim = beg + cnt - 1;
    int c = __builtin_nontemporal_load(csr + min(beg + sub, lim));   // batch-0 csr (clamped)
    int i = 0;
    for (; i + 16 <= cnt; i += 16) {    // full batches, next csr preloaded before gathers
      int cn = 0;
      if (i + 16 < cnt)                 // group-uniform
        cn = __builtin_nontemporal_load(csr + min(beg + i + 16 + sub, lim));
      u64 v_[16];
#pragma unroll
      for (int j = 0; j < 16; ++j) {
        int s = __shfl(c, shbase + j);
        v_[j] = *reinterpret_cast<const u64*>(hb + ((uint)s * 128u + (uint)sub8));
      }
#pragma unroll
      for (int j = 0; j < 16; ++j) ACCUM(v_[j]);
      c = cn;
    }
    int rem = cnt - i;                  // 0..15
    if (rem > 0) {
      if (rem <= 8) {                   // 8-slot partial (exec-masked per group)
        u64 v_[8];
#pragma unroll
        for (int j = 0; j < 8; ++j) {
          int s = __shfl(c, shbase + j);
          s = (j < rem) ? s : NN;       // row NN is all zeros
          v_[j] = *reinterpret_cast<const u64*>(hb + ((uint)s * 128u + (uint)sub8));
        }
#pragma unroll
        for (int j = 0; j < 8; ++j) ACCUM(v_[j]);
      } else {                          // 16-slot partial
        u64 v_[16];
#pragma unroll
        for (int j = 0; j < 16; ++j) {
          int s = __shfl(c, shbase + j);
          s = (j < rem) ? s : NN;
          v_[j] = *reinterpret_cast<const u64*>(hb + ((uint)s * 128u + (uint)sub8));
        }
#pragma unroll
        for (int j = 0; j < 16; ++j) ACCUM(v_[j]);
      }
    }
  }
#undef ACCUM
  float d = dis[node];
  float4 bA = *reinterpret_cast<const float4*>(bias + sub * 8);
  float4 bB = *reinterpret_cast<const float4*>(bias + sub * 8 + 4);
  float o0 = fmaxf(fmaf(d, a01[0], bA.x), 0.f);
  float o1 = fmaxf(fmaf(d, a01[1], bA.y), 0.f);
  float o2 = fmaxf(fmaf(d, a23[0], bA.z), 0.f);
  float o3 = fmaxf(fmaf(d, a23[1], bA.w), 0.f);
  float o4 = fmaxf(fmaf(d, a45[0], bB.x), 0.f);
  float o5 = fmaxf(fmaf(d, a45[1], bB.y), 0.f);
  float o6 = fmaxf(fmaf(d, a67[0], bB.z), 0.f);
  float o7 = fmaxf(fmaf(d, a67[1], bB.w), 0.f);
  uint b01 = (uint)__builtin_amdgcn_cvt_pk_fp8_f32(o0, o1, 0, false) & 0xFFFFu;
  uint b23 = (uint)__builtin_amdgcn_cvt_pk_fp8_f32(o2, o3, 0, false) & 0xFFFFu;
  uint b45 = (uint)__builtin_amdgcn_cvt_pk_fp8_f32(o4, o5, 0, false) & 0xFFFFu;
  uint b67 = (uint)__builtin_amdgcn_cvt_pk_fp8_f32(o6, o7, 0, false) & 0xFFFFu;
  u64 pk = (u64)(b01 | (b23 << 16)) | ((u64)(b45 | (b67 << 16)) << 32);
  __builtin_nontemporal_store(pk, &outb[(size_t)node * 16 + sub]);
}

// ---------------- GraphNorm stats: per-(g,f) sum & sumsq partials, fp8 input ----------------
__global__ __launch_bounds__(256) void k_stats(const uint* __restrict__ t8, const int* __restrict__ gstart,
                                               float* __restrict__ acc) {
  int g = blockIdx.x >> 4, s = blockIdx.x & 15;
  int beg = gstart[g], end = gstart[g + 1];
  int j = threadIdx.x & 31, q = threadIdx.x >> 5;   // 32 uints/row (4 feats each), 8 row-groups
  f32x2 s01 = (f32x2){0.f, 0.f}, s23 = (f32x2){0.f, 0.f};
  f32x2 q01 = (f32x2){0.f, 0.f}, q23 = (f32x2){0.f, 0.f};
  for (int n = beg + s * 8 + q; n < end; n += 128) {
    uint v = t8[(size_t)n * 32 + j];
    f32x2 f01 = __builtin_amdgcn_cvt_pk_f32_fp8((int)v, false);
    f32x2 f23 = __builtin_amdgcn_cvt_pk_f32_fp8((int)v, true);
    s01 += f01; s23 += f23;
    q01 += f01 * f01; q23 += f23 * f23;
  }
  __shared__ float shs[256][4];
  __shared__ float shq[256][4];
  int t = threadIdx.x;
  shs[t][0] = s01[0]; shs[t][1] = s01[1]; shs[t][2] = s23[0]; shs[t][3] = s23[1];
  shq[t][0] = q01[0]; shq[t][1] = q01[1]; shq[t][2] = q23[0]; shq[t][3] = q23[1];
  __syncthreads();
  if (q == 0) {
    float sm[4], sq[4];
#pragma unroll
    for (int k = 0; k < 4; ++k) { sm[k] = shs[j][k]; sq[k] = shq[j][k]; }
#pragma unroll
    for (int qq = 1; qq < 8; ++qq) {
      int idx = qq * 32 + j;
#pragma unroll
      for (int k = 0; k < 4; ++k) { sm[k] += shs[idx][k]; sq[k] += shq[idx][k]; }
    }
    int f = j * 4;
    float* dst = acc + (size_t)(s * NG + g) * 2 * NH;
#pragma unroll
    for (int k = 0; k < 4; ++k) { dst[f + k] = sm[k]; dst[NH + f + k] = sq[k]; }
  }
}

__global__ __launch_bounds__(128) void k_fin1(const float* __restrict__ acc, const int* __restrict__ counts,
                                              const float* __restrict__ gw, const float* __restrict__ gb,
                                              const float* __restrict__ ga,
                                              float* __restrict__ Aaff, float* __restrict__ Baff) {
  int g = blockIdx.x, f = threadIdx.x;
  float sum = 0.f, sq = 0.f;
#pragma unroll 4
  for (int s = 0; s < 16; ++s) {
    const float* d = acc + (size_t)(s * NG + g) * 2 * NH;
    sum += d[f];
    sq += d[NH + f];
  }
  float cnt = fmaxf((float)counts[g], 1.f);
  float m = sum / cnt;
  float ex2 = sq / cnt;
  float a = ga[f];
  float var = ex2 - 2.f * a * m * m + a * a * m * m;
  float rstd = rsqrtf(var + EPSV);
  float A = gw[f] * rstd;
  Aaff[g * NH + f] = A;
  Baff[g * NH + f] = gb[f] - A * a * m;
}

// fused layer-2 finalize + classifier head + softmax
__global__ __launch_bounds__(128) void k_fin2head(const float* __restrict__ acc, const int* __restrict__ counts,
                                                  const float* __restrict__ gw, const float* __restrict__ gb,
                                                  const float* __restrict__ ga, const float* __restrict__ Wc,
                                                  const float* __restrict__ bc, float* __restrict__ outp) {
  __shared__ float pool[NH];
  __shared__ float lg[NC];
  int g = blockIdx.x, f = threadIdx.x;
  float sum = 0.f, sq = 0.f;
#pragma unroll 4
  for (int s = 0; s < 16; ++s) {
    const float* d = acc + (size_t)(s * NG + g) * 2 * NH;
    sum += d[f];
    sq += d[NH + f];
  }
  float cnt = fmaxf((float)counts[g], 1.f);
  float m = sum / cnt;
  float ex2 = sq / cnt;
  float a = ga[f];
  float var = ex2 - 2.f * a * m * m + a * a * m * m;
  float rstd = rsqrtf(var + EPSV);
  pool[f] = gw[f] * rstd * (m - a * m) + gb[f];
  __syncthreads();
  if (f < NC) {
    float s = bc[f];
    for (int h = 0; h < NH; ++h) s = fmaf(pool[h], Wc[h * NC + f], s);
    lg[f] = s;
  }
  __syncthreads();
  if (f == 0) {
    float mx = lg[0];
    for (int c = 1; c < NC; ++c) mx = fmaxf(mx, lg[c]);
    float ex[NC];
    float ssum = 0.f;
    for (int c = 0; c < NC; ++c) { ex[c] = __expf(lg[c] - mx); ssum += ex[c]; }
    float inv = 1.f / ssum;
    for (int c = 0; c < NC; ++c) outp[g * NC + c] = ex[c] * inv;
  }
}

// ---------------- launch ----------------
extern "C" void kernel_launch(void* const* d_in, const int* in_sizes, int n_in,
                              void* d_out, int out_size, void* d_ws, size_t ws_size,
                              hipStream_t stream) {
  const float* x   = (const float*)d_in[0];
  const int*   ei  = (const int*)d_in[1];
  const int*   bat = (const int*)d_in[2];
  const float* W1  = (const float*)d_in[3];
  const float* b1  = (const float*)d_in[4];
  const float* gw1 = (const float*)d_in[5];
  const float* gb1 = (const float*)d_in[6];
  const float* ga1 = (const float*)d_in[7];
  const float* W2  = (const float*)d_in[8];
  const float* b2  = (const float*)d_in[9];
  const float* gw2 = (const float*)d_in[10];
  const float* gb2 = (const float*)d_in[11];
  const float* ga2 = (const float*)d_in[12];
  const float* Wc  = (const float*)d_in[13];
  const float* bc  = (const float*)d_in[14];
  float* outp = (float*)d_out;

  char* ws = (char*)d_ws;
  size_t off = 0;
  auto alloc = [&](size_t b) { size_t p = off; off += (b + 255) & ~(size_t)255; return p; };
  u64*    od      = (u64*)(ws + alloc((size_t)NN * 8));
  float*  dis     = (float*)(ws + alloc((size_t)NN * 4));
  int*    counts  = (int*)(ws + alloc(NG * 4));
  int*    gstart  = (int*)(ws + alloc((NG + 1) * 4));
  int*    csums   = (int*)(ws + alloc(512 * 4));
  int*    csr     = (int*)(ws + alloc((size_t)NE * 4));
  float*  statacc = (float*)(ws + alloc((size_t)16 * NG * 2 * NH * 4));   // 1 MB partials
  float*  Aaff    = (float*)(ws + alloc((size_t)NG * NH * 4));
  float*  Baff    = (float*)(ws + alloc((size_t)NG * NH * 4));
  ushort* WF1     = (ushort*)(ws + alloc((size_t)2048 * 8 * 2));
  ushort* WF2     = (ushort*)(ws + alloc((size_t)2048 * 8 * 2));
  uchar*  bufA    = (uchar*)(ws + alloc((size_t)(NN + 1) * NH));   // fp8 + zero row NN
  uchar*  bufB    = (uchar*)(ws + alloc((size_t)(NN + 1) * NH));   // fp8 + zero row NN
  // sort temps alias bufB (dead until first k_agg write): 6.4 (packed int) + 1.6 MB < 12.8 MB
  int* tmp   = (int*)bufB;
  int* ghist = (int*)((char*)bufB + (((size_t)NE * 4 + 255) & ~(size_t)255));
  (void)ws_size; (void)in_sizes; (void)n_in; (void)out_size;

  u64* zrowA = (u64*)(bufA + (size_t)NN * NH);
  u64* zrowB = (u64*)(bufB + (size_t)NN * NH);

  // prep (merged): gstart/counts + zero rows + W pre-pack + coarse hist
  k_prep0<<<529, 256, 0, stream>>>(bat, gstart, counts, zrowA, zrowB, W1, WF1, W2, WF2, ei, ghist);
  k_scan1g<<<NSB, 256, 0, stream>>>(ghist, csums);
  k_scatter<<<NBLK, 256, 0, stream>>>(ei, ghist, csums, tmp);
  k_fine<<<NB, 256, 0, stream>>>(tmp, ghist, csums, od, dis, csr);

  int gemm_grid = (NN + 63) / 64;   // 1563
  int agg_grid  = NN / 16;          // 6250 (4 nodes per wave, group-owns-node)

  // layer 1
  k_gemm<false><<<gemm_grid, 256, 0, stream>>>(x, WF1, dis, bat, nullptr, nullptr, bufA);
  k_agg<<<agg_grid, 256, 0, stream>>>(bufA, od, csr, dis, b1, (u64*)bufB);
  k_stats<<<NG * 16, 256, 0, stream>>>((const uint*)bufB, gstart, statacc);
  k_fin1<<<NG, 128, 0, stream>>>(statacc, counts, gw1, gb1, ga1, Aaff, Baff);

  // layer 2 (norm fused into GEMM A-fragment load, fp8 A-input)
  k_gemm<true><<<gemm_grid, 256, 0, stream>>>(bufB, WF2, dis, bat, Aaff, Baff, bufA);
  k_agg<<<agg_grid, 256, 0, stream>>>(bufA, od, csr, dis, b2, (u64*)bufB);
  k_stats<<<NG * 16, 256, 0, stream>>>((const uint*)bufB, gstart, statacc);
  k_fin2head<<<NG, 128, 0, stream>>>(statacc, counts, gw2, gb2, ga2, Wc, bc, outp);
}